// Round 1
// baseline (9180.280 us; speedup 1.0000x reference)
//
#include <hip/hip_runtime.h>

constexpr int N = 100000;   // nodes
constexpr int E = 1600000;  // edges
constexpr int H = 128;      // feature dim (D == H == 128)
constexpr int G = 64;       // graphs
constexpr int C = 10;       // classes

// ---------------------------------------------------------------------------
// Scatter-add: agg[dst] += h[src], 128 feats per edge.
// 32 lanes per edge, float4 per lane -> coalesced 512B gather per edge.
// ---------------------------------------------------------------------------
__global__ __launch_bounds__(256) void scatter_kernel(
    const float* __restrict__ h, const int* __restrict__ src,
    const int* __restrict__ dst, float* __restrict__ agg) {
  const int e = blockIdx.x * 8 + (threadIdx.x >> 5);
  const int l = threadIdx.x & 31;
  const int s = src[e];
  const int d = dst[e];
  const float4 v = *(const float4*)(h + (size_t)s * H + l * 4);
  float* ap = agg + (size_t)d * H + l * 4;
  atomicAdd(ap + 0, v.x);
  atomicAdd(ap + 1, v.y);
  atomicAdd(ap + 2, v.z);
  atomicAdd(ap + 3, v.w);
}

// ---------------------------------------------------------------------------
// Fused GIN MLP: pre = h_in + agg; hid = relu(pre@W1 + b1); o = hid@W2 + b2
// MODE 0: h_out = LayerNorm(relu(o))        (layers 0,1)
// MODE 1: emb = o; h_out = relu(o)          (layer 2)
// Both 128x128 weights live in LDS (128 KB); 16-node tiles; 128 thr/block;
// each thread owns a 4(node) x 4(feat) accumulator block.
// ---------------------------------------------------------------------------
template <int MODE>
__global__ __launch_bounds__(128, 1) void mlp_kernel(
    const float* __restrict__ h_in, const float* __restrict__ agg,
    const float* __restrict__ w1, const float* __restrict__ b1,
    const float* __restrict__ w2, const float* __restrict__ b2,
    const float* __restrict__ lng, const float* __restrict__ lnb,
    float* __restrict__ h_out, float* __restrict__ emb) {
  __shared__ float w1s[H * H];
  __shared__ float w2s[H * H];
  __shared__ float pre[16 * H];
  __shared__ float hid[16 * H];
  __shared__ float mu_s[16];
  __shared__ float rs_s[16];

  const int tid = threadIdx.x;

  // Stage both weight matrices into LDS (float4 coalesced).
  {
    const float4* w1v = (const float4*)w1;
    const float4* w2v = (const float4*)w2;
    float4* w1d = (float4*)w1s;
    float4* w2d = (float4*)w2s;
    for (int i = tid; i < H * H / 4; i += 128) {
      w1d[i] = w1v[i];
      w2d[i] = w2v[i];
    }
  }
  const int f0 = (tid & 31) * 4;   // 4 consecutive output features
  const int n0 = (tid >> 5) * 4;   // 4 consecutive nodes in tile
  const float4 b1v = *(const float4*)(b1 + f0);
  const float4 b2v = *(const float4*)(b2 + f0);
  __syncthreads();

  const int ntiles = N / 16;  // 6250
  for (int tile = blockIdx.x; tile < ntiles; tile += gridDim.x) {
    const size_t base = (size_t)tile * 16 * H;
    // stage pre = h + agg  (coalesced; pre[n][k] at n*128+k)
    for (int it = 0; it < 16; ++it) {
      const int idx = it * 128 + tid;
      pre[idx] = h_in[base + idx] + agg[base + idx];
    }
    __syncthreads();

    // GEMM1: hid = relu(pre @ w1 + b1)
    {
      float acc[4][4];
#pragma unroll
      for (int i = 0; i < 4; ++i)
#pragma unroll
        for (int j = 0; j < 4; ++j) acc[i][j] = 0.f;
      for (int k = 0; k < H; k += 4) {
        const float4 wa = *(const float4*)&w1s[(k + 0) * H + f0];
        const float4 wb = *(const float4*)&w1s[(k + 1) * H + f0];
        const float4 wc = *(const float4*)&w1s[(k + 2) * H + f0];
        const float4 wd = *(const float4*)&w1s[(k + 3) * H + f0];
#pragma unroll
        for (int i = 0; i < 4; ++i) {
          const float4 p = *(const float4*)&pre[(n0 + i) * H + k];
          acc[i][0] += p.x * wa.x + p.y * wb.x + p.z * wc.x + p.w * wd.x;
          acc[i][1] += p.x * wa.y + p.y * wb.y + p.z * wc.y + p.w * wd.y;
          acc[i][2] += p.x * wa.z + p.y * wb.z + p.z * wc.z + p.w * wd.z;
          acc[i][3] += p.x * wa.w + p.y * wb.w + p.z * wc.w + p.w * wd.w;
        }
      }
#pragma unroll
      for (int i = 0; i < 4; ++i) {
        float4 r;
        r.x = fmaxf(acc[i][0] + b1v.x, 0.f);
        r.y = fmaxf(acc[i][1] + b1v.y, 0.f);
        r.z = fmaxf(acc[i][2] + b1v.z, 0.f);
        r.w = fmaxf(acc[i][3] + b1v.w, 0.f);
        *(float4*)&hid[(n0 + i) * H + f0] = r;
      }
    }
    __syncthreads();

    // GEMM2: o = hid @ w2 + b2 ; write relu(o) (MODE 0) or o (MODE 1) into pre
    {
      float acc[4][4];
#pragma unroll
      for (int i = 0; i < 4; ++i)
#pragma unroll
        for (int j = 0; j < 4; ++j) acc[i][j] = 0.f;
      for (int k = 0; k < H; k += 4) {
        const float4 wa = *(const float4*)&w2s[(k + 0) * H + f0];
        const float4 wb = *(const float4*)&w2s[(k + 1) * H + f0];
        const float4 wc = *(const float4*)&w2s[(k + 2) * H + f0];
        const float4 wd = *(const float4*)&w2s[(k + 3) * H + f0];
#pragma unroll
        for (int i = 0; i < 4; ++i) {
          const float4 p = *(const float4*)&hid[(n0 + i) * H + k];
          acc[i][0] += p.x * wa.x + p.y * wb.x + p.z * wc.x + p.w * wd.x;
          acc[i][1] += p.x * wa.y + p.y * wb.y + p.z * wc.y + p.w * wd.y;
          acc[i][2] += p.x * wa.z + p.y * wb.z + p.z * wc.z + p.w * wd.z;
          acc[i][3] += p.x * wa.w + p.y * wb.w + p.z * wc.w + p.w * wd.w;
        }
      }
#pragma unroll
      for (int i = 0; i < 4; ++i) {
        float o0 = acc[i][0] + b2v.x;
        float o1 = acc[i][1] + b2v.y;
        float o2 = acc[i][2] + b2v.z;
        float o3 = acc[i][3] + b2v.w;
        float4 r;
        if (MODE == 0) {  // store relu(o) for LN stats
          r.x = fmaxf(o0, 0.f); r.y = fmaxf(o1, 0.f);
          r.z = fmaxf(o2, 0.f); r.w = fmaxf(o3, 0.f);
        } else {          // store raw o (emb needs pre-relu)
          r.x = o0; r.y = o1; r.z = o2; r.w = o3;
        }
        *(float4*)&pre[(n0 + i) * H + f0] = r;
      }
    }
    __syncthreads();

    if (MODE == 0) {
      // LayerNorm over relu'd values in `pre`
      const int n = tid >> 3;  // node 0..15
      const int j = tid & 7;   // 8 partial lanes per node
      float s = 0.f, sq = 0.f;
#pragma unroll
      for (int t = 0; t < 16; ++t) {
        const float v = pre[n * H + j + 8 * t];
        s += v;
        sq += v * v;
      }
      s += __shfl_xor(s, 1); sq += __shfl_xor(sq, 1);
      s += __shfl_xor(s, 2); sq += __shfl_xor(sq, 2);
      s += __shfl_xor(s, 4); sq += __shfl_xor(sq, 4);
      if (j == 0) {
        const float mu = s * (1.f / H);
        const float var = sq * (1.f / H) - mu * mu;
        mu_s[n] = mu;
        rs_s[n] = rsqrtf(var + 1e-5f);
      }
      __syncthreads();
      for (int it = 0; it < 16; ++it) {
        const int idx = it * 128 + tid;
        const int nn = idx >> 7;
        const int k = idx & 127;
        const float r = pre[idx];
        h_out[base + idx] = (r - mu_s[nn]) * rs_s[nn] * lng[k] + lnb[k];
      }
    } else {
      for (int it = 0; it < 16; ++it) {
        const int idx = it * 128 + tid;
        const float o = pre[idx];
        emb[base + idx] = o;
        h_out[base + idx] = fmaxf(o, 0.f);
      }
    }
    __syncthreads();  // protect pre/hid before next tile overwrites
  }
}

// ---------------------------------------------------------------------------
// Mean-pool prep: batch is sorted, so run-length accumulate per chunk and
// flush one atomic per (graph-run, feature). cnt accumulated by lane f==0.
// ---------------------------------------------------------------------------
constexpr int POOL_CHUNK = 512;
__global__ __launch_bounds__(128) void pool_kernel(
    const float* __restrict__ h, const int* __restrict__ batch,
    float* __restrict__ pooled, float* __restrict__ cnt) {
  const int f = threadIdx.x;
  const int s0 = blockIdx.x * POOL_CHUNK;
  const int s1 = min(s0 + POOL_CHUNK, N);
  float acc = 0.f;
  float c = 0.f;
  int cur = batch[s0];
  for (int n = s0; n < s1; ++n) {
    const int b = batch[n];
    if (b != cur) {  // wave-uniform branch
      atomicAdd(&pooled[cur * H + f], acc);
      if (f == 0) atomicAdd(&cnt[cur], c);
      acc = 0.f;
      c = 0.f;
      cur = b;
    }
    acc += h[(size_t)n * H + f];
    c += 1.f;
  }
  atomicAdd(&pooled[cur * H + f], acc);
  if (f == 0) atomicAdd(&cnt[cur], c);
}

// ---------------------------------------------------------------------------
// Head: pooled/cnt -> z = pooled@pw1+pb1 -> logits = z@pw2+pb2 -> log_softmax
// One block per graph.
// ---------------------------------------------------------------------------
__global__ __launch_bounds__(128) void head_kernel(
    const float* __restrict__ pooled, const float* __restrict__ cnt,
    const float* __restrict__ pw1, const float* __restrict__ pb1,
    const float* __restrict__ pw2, const float* __restrict__ pb2,
    float* __restrict__ out_logp) {
  __shared__ float p[H];
  __shared__ float z[H];
  __shared__ float l[C];
  const int g = blockIdx.x;
  const int f = threadIdx.x;
  const float c = fmaxf(cnt[g], 1.f);
  p[f] = pooled[g * H + f] / c;
  __syncthreads();
  float a = pb1[f];
  for (int k = 0; k < H; ++k) a += p[k] * pw1[k * H + f];
  z[f] = a;
  __syncthreads();
  if (f < C) {
    float a2 = pb2[f];
    for (int k = 0; k < H; ++k) a2 += z[k] * pw2[k * C + f];
    l[f] = a2;
  }
  __syncthreads();
  if (f == 0) {
    float m = l[0];
    for (int i = 1; i < C; ++i) m = fmaxf(m, l[i]);
    float s = 0.f;
    for (int i = 0; i < C; ++i) s += expf(l[i] - m);
    const float lse = m + logf(s);
    for (int i = 0; i < C; ++i) out_logp[g * C + i] = l[i] - lse;
  }
}

extern "C" void kernel_launch(void* const* d_in, const int* in_sizes, int n_in,
                              void* d_out, int out_size, void* d_ws,
                              size_t ws_size, hipStream_t stream) {
  const float* x = (const float*)d_in[0];
  const int* ei = (const int*)d_in[1];
  const int* src = ei;
  const int* dst = ei + E;
  const int* batch = (const int*)d_in[2];
  const float* w1_0 = (const float*)d_in[3];
  const float* b1_0 = (const float*)d_in[4];
  const float* w2_0 = (const float*)d_in[5];
  const float* b2_0 = (const float*)d_in[6];
  const float* w1_1 = (const float*)d_in[7];
  const float* b1_1 = (const float*)d_in[8];
  const float* w2_1 = (const float*)d_in[9];
  const float* b2_1 = (const float*)d_in[10];
  const float* w1_2 = (const float*)d_in[11];
  const float* b1_2 = (const float*)d_in[12];
  const float* w2_2 = (const float*)d_in[13];
  const float* b2_2 = (const float*)d_in[14];
  const float* ln_g0 = (const float*)d_in[15];
  const float* ln_b0 = (const float*)d_in[16];
  const float* ln_g1 = (const float*)d_in[17];
  const float* ln_b1 = (const float*)d_in[18];
  const float* pw1 = (const float*)d_in[19];
  const float* pb1 = (const float*)d_in[20];
  const float* pw2 = (const float*)d_in[21];
  const float* pb2 = (const float*)d_in[22];

  float* ws = (float*)d_ws;
  float* hbuf = ws;                          // N*H
  float* agg = ws + (size_t)N * H;           // N*H
  float* pooled = agg + (size_t)N * H;       // G*H
  float* cnt = pooled + (size_t)G * H;       // G
  float* emb = (float*)d_out;                // N*H
  float* logp = emb + (size_t)N * H;         // G*C

  const size_t aggBytes = (size_t)N * H * sizeof(float);

  // ---- conv 0 (reads x) ----
  hipMemsetAsync(agg, 0, aggBytes, stream);
  scatter_kernel<<<E / 8, 256, 0, stream>>>(x, src, dst, agg);
  mlp_kernel<0><<<256, 128, 0, stream>>>(x, agg, w1_0, b1_0, w2_0, b2_0,
                                         ln_g0, ln_b0, hbuf, nullptr);
  // ---- conv 1 ----
  hipMemsetAsync(agg, 0, aggBytes, stream);
  scatter_kernel<<<E / 8, 256, 0, stream>>>(hbuf, src, dst, agg);
  mlp_kernel<0><<<256, 128, 0, stream>>>(hbuf, agg, w1_1, b1_1, w2_1, b2_1,
                                         ln_g1, ln_b1, hbuf, nullptr);
  // ---- conv 2 (emits emb; h = relu(emb) for pooling) ----
  hipMemsetAsync(agg, 0, aggBytes, stream);
  scatter_kernel<<<E / 8, 256, 0, stream>>>(hbuf, src, dst, agg);
  mlp_kernel<1><<<256, 128, 0, stream>>>(hbuf, agg, w1_2, b1_2, w2_2, b2_2,
                                         nullptr, nullptr, hbuf, emb);
  // ---- global mean pool + head ----
  hipMemsetAsync(pooled, 0, (size_t)(G * H + G) * sizeof(float), stream);
  pool_kernel<<<(N + POOL_CHUNK - 1) / POOL_CHUNK, 128, 0, stream>>>(
      hbuf, batch, pooled, cnt);
  head_kernel<<<G, 128, 0, stream>>>(pooled, cnt, pw1, pb1, pw2, pb2, logp);
}

// Round 2
// 1529.852 us; speedup vs baseline: 6.0008x; 6.0008x over previous
//
#include <hip/hip_runtime.h>

constexpr int N = 100000;   // nodes
constexpr int E = 1600000;  // edges
constexpr int H = 128;      // feature dim (D == H == 128)
constexpr int G = 64;       // graphs
constexpr int C = 10;       // classes

// ---------------------------------------------------------------------------
// CSR build: deg histogram -> exclusive scan -> bucket fill.
// ---------------------------------------------------------------------------
__global__ __launch_bounds__(256) void hist_kernel(const int* __restrict__ dst,
                                                   int* __restrict__ deg) {
  const int e = blockIdx.x * 256 + threadIdx.x;
  if (e < E) atomicAdd(&deg[dst[e]], 1);
}

__global__ __launch_bounds__(1024) void scan_kernel(const int* __restrict__ deg,
                                                    int* __restrict__ rowptr,
                                                    int* __restrict__ cursor) {
  __shared__ int part[1024];
  const int t = threadIdx.x;
  constexpr int CHUNK = (N + 1023) / 1024;  // 98
  const int s0 = t * CHUNK;
  const int s1 = min(s0 + CHUNK, N);
  int sum = 0;
  for (int i = s0; i < s1; ++i) sum += deg[i];
  part[t] = sum;
  __syncthreads();
  for (int off = 1; off < 1024; off <<= 1) {
    int v = 0;
    if (t >= off) v = part[t - off];
    __syncthreads();
    if (t >= off) part[t] += v;
    __syncthreads();
  }
  int running = (t == 0) ? 0 : part[t - 1];
  for (int i = s0; i < s1; ++i) {
    rowptr[i] = running;
    cursor[i] = running;
    running += deg[i];
  }
  if (s1 == N && s0 < N) rowptr[N] = running;  // == E
}

__global__ __launch_bounds__(256) void fill_kernel(const int* __restrict__ src,
                                                   const int* __restrict__ dst,
                                                   int* __restrict__ cursor,
                                                   int* __restrict__ csr_src) {
  const int e = blockIdx.x * 256 + threadIdx.x;
  if (e < E) {
    const int slot = atomicAdd(&cursor[dst[e]], 1);
    csr_src[slot] = src[e];
  }
}

// ---------------------------------------------------------------------------
// Gather aggregation: pre[i] = h[i] + sum_{j in nbrs(i)} h[j]
// 32 lanes per node (float4/lane = full 512B row), 8 nodes per block.
// No atomics; fully overwrites pre (no memset needed).
// ---------------------------------------------------------------------------
__global__ __launch_bounds__(256) void gather_kernel(
    const float* __restrict__ h, const int* __restrict__ rowptr,
    const int* __restrict__ csr_src, float* __restrict__ pre) {
  const int node = blockIdx.x * 8 + (threadIdx.x >> 5);
  const int l = threadIdx.x & 31;
  if (node >= N) return;
  const int r0 = rowptr[node];
  const int r1 = rowptr[node + 1];
  float4 acc = *(const float4*)(h + (size_t)node * H + l * 4);
  for (int s = r0; s < r1; ++s) {
    const int sn = csr_src[s];
    const float4 v = *(const float4*)(h + (size_t)sn * H + l * 4);
    acc.x += v.x; acc.y += v.y; acc.z += v.z; acc.w += v.w;
  }
  *(float4*)(pre + (size_t)node * H + l * 4) = acc;
}

// ---------------------------------------------------------------------------
// Fused GIN MLP: hid = relu(pre@W1 + b1); o = hid@W2 + b2
// MODE 0: h_out = LayerNorm(relu(o))        (layers 0,1)
// MODE 1: emb = o; h_out = relu(o)          (layer 2)
// 256 threads, 32-node tiles, both weights in LDS. LDS = exactly 160 KB;
// LN stats live in the (free after GEMM2) hid buffer.
// ---------------------------------------------------------------------------
template <int MODE>
__global__ __launch_bounds__(256, 1) void mlp_kernel(
    const float* __restrict__ pre_g,
    const float* __restrict__ w1, const float* __restrict__ b1,
    const float* __restrict__ w2, const float* __restrict__ b2,
    const float* __restrict__ lng, const float* __restrict__ lnb,
    float* __restrict__ h_out, float* __restrict__ emb) {
  __shared__ float w1s[H * H];      // 64 KB
  __shared__ float w2s[H * H];      // 64 KB
  __shared__ float pre[32 * H];     // 16 KB
  __shared__ float hid[32 * H];     // 16 KB  (reused for LN mu/rs)

  const int tid = threadIdx.x;

  {
    const float4* w1v = (const float4*)w1;
    const float4* w2v = (const float4*)w2;
    float4* w1d = (float4*)w1s;
    float4* w2d = (float4*)w2s;
    for (int i = tid; i < H * H / 4; i += 256) {
      w1d[i] = w1v[i];
      w2d[i] = w2v[i];
    }
  }
  const int f0 = (tid & 31) * 4;   // 4 consecutive output features
  const int n0 = (tid >> 5) * 4;   // 4 consecutive nodes in tile
  const float4 b1v = *(const float4*)(b1 + f0);
  const float4 b2v = *(const float4*)(b2 + f0);
  __syncthreads();

  const int ntiles = N / 32;  // 3125
  for (int tile = blockIdx.x; tile < ntiles; tile += gridDim.x) {
    const size_t base = (size_t)tile * 32 * H;
    for (int it = 0; it < 16; ++it) {
      const int idx = it * 256 + tid;
      pre[idx] = pre_g[base + idx];
    }
    __syncthreads();

    // GEMM1: hid = relu(pre @ w1 + b1)
    {
      float acc[4][4];
#pragma unroll
      for (int i = 0; i < 4; ++i)
#pragma unroll
        for (int j = 0; j < 4; ++j) acc[i][j] = 0.f;
      for (int k = 0; k < H; k += 4) {
        const float4 wa = *(const float4*)&w1s[(k + 0) * H + f0];
        const float4 wb = *(const float4*)&w1s[(k + 1) * H + f0];
        const float4 wc = *(const float4*)&w1s[(k + 2) * H + f0];
        const float4 wd = *(const float4*)&w1s[(k + 3) * H + f0];
#pragma unroll
        for (int i = 0; i < 4; ++i) {
          const float4 p = *(const float4*)&pre[(n0 + i) * H + k];
          acc[i][0] += p.x * wa.x + p.y * wb.x + p.z * wc.x + p.w * wd.x;
          acc[i][1] += p.x * wa.y + p.y * wb.y + p.z * wc.y + p.w * wd.y;
          acc[i][2] += p.x * wa.z + p.y * wb.z + p.z * wc.z + p.w * wd.z;
          acc[i][3] += p.x * wa.w + p.y * wb.w + p.z * wc.w + p.w * wd.w;
        }
      }
#pragma unroll
      for (int i = 0; i < 4; ++i) {
        float4 r;
        r.x = fmaxf(acc[i][0] + b1v.x, 0.f);
        r.y = fmaxf(acc[i][1] + b1v.y, 0.f);
        r.z = fmaxf(acc[i][2] + b1v.z, 0.f);
        r.w = fmaxf(acc[i][3] + b1v.w, 0.f);
        *(float4*)&hid[(n0 + i) * H + f0] = r;
      }
    }
    __syncthreads();

    // GEMM2: o = hid @ w2 + b2 ; store relu(o) (MODE 0) or o (MODE 1) in pre
    {
      float acc[4][4];
#pragma unroll
      for (int i = 0; i < 4; ++i)
#pragma unroll
        for (int j = 0; j < 4; ++j) acc[i][j] = 0.f;
      for (int k = 0; k < H; k += 4) {
        const float4 wa = *(const float4*)&w2s[(k + 0) * H + f0];
        const float4 wb = *(const float4*)&w2s[(k + 1) * H + f0];
        const float4 wc = *(const float4*)&w2s[(k + 2) * H + f0];
        const float4 wd = *(const float4*)&w2s[(k + 3) * H + f0];
#pragma unroll
        for (int i = 0; i < 4; ++i) {
          const float4 p = *(const float4*)&hid[(n0 + i) * H + k];
          acc[i][0] += p.x * wa.x + p.y * wb.x + p.z * wc.x + p.w * wd.x;
          acc[i][1] += p.x * wa.y + p.y * wb.y + p.z * wc.y + p.w * wd.y;
          acc[i][2] += p.x * wa.z + p.y * wb.z + p.z * wc.z + p.w * wd.z;
          acc[i][3] += p.x * wa.w + p.y * wb.w + p.z * wc.w + p.w * wd.w;
        }
      }
      __syncthreads();  // everyone done reading hid (needed before LN reuse)
#pragma unroll
      for (int i = 0; i < 4; ++i) {
        float o0 = acc[i][0] + b2v.x;
        float o1 = acc[i][1] + b2v.y;
        float o2 = acc[i][2] + b2v.z;
        float o3 = acc[i][3] + b2v.w;
        float4 r;
        if (MODE == 0) {
          r.x = fmaxf(o0, 0.f); r.y = fmaxf(o1, 0.f);
          r.z = fmaxf(o2, 0.f); r.w = fmaxf(o3, 0.f);
        } else {
          r.x = o0; r.y = o1; r.z = o2; r.w = o3;
        }
        *(float4*)&pre[(n0 + i) * H + f0] = r;
      }
    }
    __syncthreads();

    if (MODE == 0) {
      // LayerNorm over relu'd values in `pre`; stats stored in hid[0..63]
      const int n = tid >> 3;  // node 0..31
      const int j = tid & 7;   // 8 partial lanes per node
      float s = 0.f, sq = 0.f;
#pragma unroll
      for (int t = 0; t < 16; ++t) {
        const float v = pre[n * H + j + 8 * t];
        s += v;
        sq += v * v;
      }
      s += __shfl_xor(s, 1); sq += __shfl_xor(sq, 1);
      s += __shfl_xor(s, 2); sq += __shfl_xor(sq, 2);
      s += __shfl_xor(s, 4); sq += __shfl_xor(sq, 4);
      if (j == 0) {
        const float mu = s * (1.f / H);
        const float var = sq * (1.f / H) - mu * mu;
        hid[n] = mu;
        hid[32 + n] = rsqrtf(var + 1e-5f);
      }
      __syncthreads();
      for (int it = 0; it < 16; ++it) {
        const int idx = it * 256 + tid;
        const int nn = idx >> 7;
        const int k = idx & 127;
        const float r = pre[idx];
        h_out[base + idx] = (r - hid[nn]) * hid[32 + nn] * lng[k] + lnb[k];
      }
    } else {
      for (int it = 0; it < 16; ++it) {
        const int idx = it * 256 + tid;
        const float o = pre[idx];
        emb[base + idx] = o;
        h_out[base + idx] = fmaxf(o, 0.f);
      }
    }
    __syncthreads();  // protect pre/hid before next tile overwrites
  }
}

// ---------------------------------------------------------------------------
// Mean-pool prep: batch sorted -> run-length accumulate, flush per run.
// ---------------------------------------------------------------------------
constexpr int POOL_CHUNK = 512;
__global__ __launch_bounds__(128) void pool_kernel(
    const float* __restrict__ h, const int* __restrict__ batch,
    float* __restrict__ pooled, float* __restrict__ cnt) {
  const int f = threadIdx.x;
  const int s0 = blockIdx.x * POOL_CHUNK;
  const int s1 = min(s0 + POOL_CHUNK, N);
  float acc = 0.f;
  float c = 0.f;
  int cur = batch[s0];
  for (int n = s0; n < s1; ++n) {
    const int b = batch[n];
    if (b != cur) {
      atomicAdd(&pooled[cur * H + f], acc);
      if (f == 0) atomicAdd(&cnt[cur], c);
      acc = 0.f;
      c = 0.f;
      cur = b;
    }
    acc += h[(size_t)n * H + f];
    c += 1.f;
  }
  atomicAdd(&pooled[cur * H + f], acc);
  if (f == 0) atomicAdd(&cnt[cur], c);
}

// ---------------------------------------------------------------------------
// Head: pooled/cnt -> z = pooled@pw1+pb1 -> logits -> log_softmax
// ---------------------------------------------------------------------------
__global__ __launch_bounds__(128) void head_kernel(
    const float* __restrict__ pooled, const float* __restrict__ cnt,
    const float* __restrict__ pw1, const float* __restrict__ pb1,
    const float* __restrict__ pw2, const float* __restrict__ pb2,
    float* __restrict__ out_logp) {
  __shared__ float p[H];
  __shared__ float z[H];
  __shared__ float l[C];
  const int g = blockIdx.x;
  const int f = threadIdx.x;
  const float c = fmaxf(cnt[g], 1.f);
  p[f] = pooled[g * H + f] / c;
  __syncthreads();
  float a = pb1[f];
  for (int k = 0; k < H; ++k) a += p[k] * pw1[k * H + f];
  z[f] = a;
  __syncthreads();
  if (f < C) {
    float a2 = pb2[f];
    for (int k = 0; k < H; ++k) a2 += z[k] * pw2[k * C + f];
    l[f] = a2;
  }
  __syncthreads();
  if (f == 0) {
    float m = l[0];
    for (int i = 1; i < C; ++i) m = fmaxf(m, l[i]);
    float s = 0.f;
    for (int i = 0; i < C; ++i) s += expf(l[i] - m);
    const float lse = m + logf(s);
    for (int i = 0; i < C; ++i) out_logp[g * C + i] = l[i] - lse;
  }
}

extern "C" void kernel_launch(void* const* d_in, const int* in_sizes, int n_in,
                              void* d_out, int out_size, void* d_ws,
                              size_t ws_size, hipStream_t stream) {
  const float* x = (const float*)d_in[0];
  const int* ei = (const int*)d_in[1];
  const int* src = ei;
  const int* dst = ei + E;
  const int* batch = (const int*)d_in[2];
  const float* w1_0 = (const float*)d_in[3];
  const float* b1_0 = (const float*)d_in[4];
  const float* w2_0 = (const float*)d_in[5];
  const float* b2_0 = (const float*)d_in[6];
  const float* w1_1 = (const float*)d_in[7];
  const float* b1_1 = (const float*)d_in[8];
  const float* w2_1 = (const float*)d_in[9];
  const float* b2_1 = (const float*)d_in[10];
  const float* w1_2 = (const float*)d_in[11];
  const float* b1_2 = (const float*)d_in[12];
  const float* w2_2 = (const float*)d_in[13];
  const float* b2_2 = (const float*)d_in[14];
  const float* ln_g0 = (const float*)d_in[15];
  const float* ln_b0 = (const float*)d_in[16];
  const float* ln_g1 = (const float*)d_in[17];
  const float* ln_b1 = (const float*)d_in[18];
  const float* pw1 = (const float*)d_in[19];
  const float* pb1 = (const float*)d_in[20];
  const float* pw2 = (const float*)d_in[21];
  const float* pb2 = (const float*)d_in[22];

  float* ws = (float*)d_ws;
  float* hbuf = ws;                          // N*H floats
  float* pre = ws + (size_t)N * H;           // N*H floats
  float* pooled = pre + (size_t)N * H;       // G*H
  float* cnt = pooled + (size_t)G * H;       // G
  int* ibase = (int*)(cnt + G);
  int* deg = ibase;                          // N
  int* rowptr = deg + N;                     // N+1
  int* cursor = rowptr + N + 1;              // N
  int* csr_src = cursor + N;                 // E
  float* emb = (float*)d_out;                // N*H
  float* logp = emb + (size_t)N * H;         // G*C

  // ---- CSR build (once per call) ----
  hipMemsetAsync(deg, 0, (size_t)N * sizeof(int), stream);
  hist_kernel<<<(E + 255) / 256, 256, 0, stream>>>(dst, deg);
  scan_kernel<<<1, 1024, 0, stream>>>(deg, rowptr, cursor);
  fill_kernel<<<(E + 255) / 256, 256, 0, stream>>>(src, dst, cursor, csr_src);

  // ---- conv 0 (reads x) ----
  gather_kernel<<<N / 8, 256, 0, stream>>>(x, rowptr, csr_src, pre);
  mlp_kernel<0><<<256, 256, 0, stream>>>(pre, w1_0, b1_0, w2_0, b2_0,
                                         ln_g0, ln_b0, hbuf, nullptr);
  // ---- conv 1 ----
  gather_kernel<<<N / 8, 256, 0, stream>>>(hbuf, rowptr, csr_src, pre);
  mlp_kernel<0><<<256, 256, 0, stream>>>(pre, w1_1, b1_1, w2_1, b2_1,
                                         ln_g1, ln_b1, hbuf, nullptr);
  // ---- conv 2 (emits emb; h = relu(emb) for pooling) ----
  gather_kernel<<<N / 8, 256, 0, stream>>>(hbuf, rowptr, csr_src, pre);
  mlp_kernel<1><<<256, 256, 0, stream>>>(pre, w1_2, b1_2, w2_2, b2_2,
                                         nullptr, nullptr, hbuf, emb);
  // ---- global mean pool + head ----
  hipMemsetAsync(pooled, 0, (size_t)(G * H + G) * sizeof(float), stream);
  pool_kernel<<<(N + POOL_CHUNK - 1) / POOL_CHUNK, 128, 0, stream>>>(
      hbuf, batch, pooled, cnt);
  head_kernel<<<G, 128, 0, stream>>>(pooled, cnt, pw1, pb1, pw2, pb2, logp);
}

// Round 3
// 763.649 us; speedup vs baseline: 12.0216x; 2.0033x over previous
//
#include <hip/hip_runtime.h>

typedef __bf16 bf16_t;
typedef __bf16 bf16x8 __attribute__((ext_vector_type(8)));
typedef float floatx4 __attribute__((ext_vector_type(4)));

constexpr int N = 100000;   // nodes
constexpr int E = 1600000;  // edges
constexpr int H = 128;      // feature dim
constexpr int G = 64;       // graphs
constexpr int C = 10;       // classes
constexpr int NBLK = (N + 255) / 256;  // 391

__device__ inline float bflo(unsigned u) {
  return __builtin_bit_cast(float, u << 16);
}
__device__ inline float bfhi(unsigned u) {
  return __builtin_bit_cast(float, u & 0xffff0000u);
}
__device__ inline unsigned short f2b(float f) {
  return __builtin_bit_cast(unsigned short, (bf16_t)f);
}
__device__ inline unsigned pack2(float a, float b) {
  return (unsigned)f2b(a) | ((unsigned)f2b(b) << 16);
}
__device__ inline float b2f(unsigned short u) {
  return __builtin_bit_cast(float, (unsigned)u << 16);
}

// ---------------------------------------------------------------------------
// fp32 -> bf16 convert (x once per call). 8 floats/thread.
// ---------------------------------------------------------------------------
__global__ __launch_bounds__(256) void tobf_kernel(const float* __restrict__ x,
                                                   uint4* __restrict__ xb) {
  const int g = blockIdx.x * 256 + threadIdx.x;
  const float4 a = *(const float4*)(x + (size_t)g * 8);
  const float4 b = *(const float4*)(x + (size_t)g * 8 + 4);
  uint4 o;
  o.x = pack2(a.x, a.y);
  o.y = pack2(a.z, a.w);
  o.z = pack2(b.x, b.y);
  o.w = pack2(b.z, b.w);
  xb[g] = o;
}

// ---------------------------------------------------------------------------
// CSR build: histogram -> parallel 3-phase scan -> bucket fill.
// ---------------------------------------------------------------------------
__global__ __launch_bounds__(256) void hist_kernel(const int* __restrict__ dst,
                                                   int* __restrict__ deg) {
  const int e = blockIdx.x * 256 + threadIdx.x;
  if (e < E) atomicAdd(&deg[dst[e]], 1);
}

__global__ __launch_bounds__(256) void partial_kernel(
    const int* __restrict__ deg, int* __restrict__ partials) {
  __shared__ int sm[256];
  const int tid = threadIdx.x;
  const int i = blockIdx.x * 256 + tid;
  sm[tid] = (i < N) ? deg[i] : 0;
  __syncthreads();
  for (int off = 128; off > 0; off >>= 1) {
    if (tid < off) sm[tid] += sm[tid + off];
    __syncthreads();
  }
  if (tid == 0) partials[blockIdx.x] = sm[0];
}

__global__ __launch_bounds__(512) void scanp_kernel(
    const int* __restrict__ partials, int* __restrict__ blockbase) {
  __shared__ int p[512];
  const int t = threadIdx.x;
  p[t] = (t < NBLK) ? partials[t] : 0;
  __syncthreads();
  for (int off = 1; off < 512; off <<= 1) {
    int v = 0;
    if (t >= off) v = p[t - off];
    __syncthreads();
    p[t] += v;
    __syncthreads();
  }
  if (t < NBLK) blockbase[t] = (t == 0) ? 0 : p[t - 1];
}

__global__ __launch_bounds__(256) void expand_kernel(
    const int* __restrict__ deg, const int* __restrict__ blockbase,
    int* __restrict__ rowptr, int* __restrict__ cursor) {
  __shared__ int sm[256];
  const int tid = threadIdx.x;
  const int i = blockIdx.x * 256 + tid;
  const int d = (i < N) ? deg[i] : 0;
  sm[tid] = d;
  __syncthreads();
  for (int off = 1; off < 256; off <<= 1) {
    int v = 0;
    if (tid >= off) v = sm[tid - off];
    __syncthreads();
    sm[tid] += v;
    __syncthreads();
  }
  const int excl = sm[tid] - d + blockbase[blockIdx.x];
  if (i < N) {
    rowptr[i] = excl;
    cursor[i] = excl;
  }
  if (i == N - 1) rowptr[N] = excl + d;
}

__global__ __launch_bounds__(256) void fill_kernel(const int* __restrict__ src,
                                                   const int* __restrict__ dst,
                                                   int* __restrict__ cursor,
                                                   int* __restrict__ csr_src) {
  const int e = blockIdx.x * 256 + threadIdx.x;
  if (e < E) {
    const int slot = atomicAdd(&cursor[dst[e]], 1);
    csr_src[slot] = src[e];
  }
}

// ---------------------------------------------------------------------------
// Gather aggregation (bf16): pre[i] = h[i] + sum_{j in nbrs(i)} h[j]
// 16 lanes per node, uint4 (8 bf16) per lane. fp32 accumulate, bf16 out.
// ---------------------------------------------------------------------------
__global__ __launch_bounds__(256) void gather_kernel(
    const uint4* __restrict__ h, const int* __restrict__ rowptr,
    const int* __restrict__ csr_src, uint4* __restrict__ pre) {
  const int node = blockIdx.x * 16 + (threadIdx.x >> 4);
  const int l = threadIdx.x & 15;
  const int r0 = rowptr[node];
  const int r1 = rowptr[node + 1];
  uint4 v = h[node * 16 + l];
  float a0 = bflo(v.x), a1 = bfhi(v.x), a2 = bflo(v.y), a3 = bfhi(v.y);
  float a4 = bflo(v.z), a5 = bfhi(v.z), a6 = bflo(v.w), a7 = bfhi(v.w);
  int s = r0;
  for (; s + 1 < r1; s += 2) {
    const uint4 u = h[csr_src[s] * 16 + l];
    const uint4 w = h[csr_src[s + 1] * 16 + l];
    a0 += bflo(u.x); a1 += bfhi(u.x); a2 += bflo(u.y); a3 += bfhi(u.y);
    a4 += bflo(u.z); a5 += bfhi(u.z); a6 += bflo(u.w); a7 += bfhi(u.w);
    a0 += bflo(w.x); a1 += bfhi(w.x); a2 += bflo(w.y); a3 += bfhi(w.y);
    a4 += bflo(w.z); a5 += bfhi(w.z); a6 += bflo(w.w); a7 += bfhi(w.w);
  }
  if (s < r1) {
    const uint4 u = h[csr_src[s] * 16 + l];
    a0 += bflo(u.x); a1 += bfhi(u.x); a2 += bflo(u.y); a3 += bfhi(u.y);
    a4 += bflo(u.z); a5 += bfhi(u.z); a6 += bflo(u.w); a7 += bfhi(u.w);
  }
  uint4 o;
  o.x = pack2(a0, a1);
  o.y = pack2(a2, a3);
  o.z = pack2(a4, a5);
  o.w = pack2(a6, a7);
  pre[node * 16 + l] = o;
}

// ---------------------------------------------------------------------------
// MFMA bf16 GIN MLP. 32-node tiles; W1/W2 fragments in registers (loaded once
// per persistent block); pre/hid in LDS padded to 136 shorts (2-way bank
// aliasing = free). mfma_f32_16x16x32_bf16: A[m=lane&15][k=quad*8+j],
// B[k=quad*8+j][n=lane&15], C/D col=lane&15 row=quad*4+reg.
// MODE 0: h_out = bf16(LayerNorm(relu(o)))     (layers 0,1)
// MODE 1: emb = fp32 o; h_out = bf16(relu(o))  (layer 2)
// ---------------------------------------------------------------------------
template <int MODE>
__global__ __launch_bounds__(256, 1) void mlp_kernel(
    const unsigned short* __restrict__ pre_g,  // bf16 N x 128
    const float* __restrict__ w1, const float* __restrict__ b1,
    const float* __restrict__ w2, const float* __restrict__ b2,
    const float* __restrict__ lng, const float* __restrict__ lnb,
    unsigned short* __restrict__ h_out,        // bf16 N x 128
    float* __restrict__ emb) {
  __shared__ unsigned short preS[32 * 136];
  __shared__ unsigned short hidS[32 * 136];
  __shared__ float outS[32 * 128];
  __shared__ float muS[32];
  __shared__ float rsS[32];

  const int tid = threadIdx.x;
  const int wave = tid >> 6;
  const int lane = tid & 63;
  const int quad = lane >> 4;
  const int l16 = lane & 15;

  union F8 { bf16x8 v; bf16_t e[8]; };

  // Weight fragments in registers (once per block).
  bf16x8 w1f[4][2], w2f[4][2];
#pragma unroll
  for (int nn = 0; nn < 2; ++nn) {
    const int col = wave * 32 + nn * 16 + l16;
#pragma unroll
    for (int kt = 0; kt < 4; ++kt) {
      F8 t1, t2;
#pragma unroll
      for (int j = 0; j < 8; ++j) {
        const int k = kt * 32 + quad * 8 + j;
        t1.e[j] = (bf16_t)w1[k * H + col];
        t2.e[j] = (bf16_t)w2[k * H + col];
      }
      w1f[kt][nn] = t1.v;
      w2f[kt][nn] = t2.v;
    }
  }
  const float b1v[2] = {b1[wave * 32 + l16], b1[wave * 32 + 16 + l16]};
  const float b2v[2] = {b2[wave * 32 + l16], b2[wave * 32 + 16 + l16]};
  float lng0 = 0.f, lng1 = 0.f, lnb0 = 0.f, lnb1 = 0.f;
  const int c2 = (tid * 2) & 127;
  if (MODE == 0) {
    lng0 = lng[c2]; lng1 = lng[c2 + 1];
    lnb0 = lnb[c2]; lnb1 = lnb[c2 + 1];
  }

  for (int tile = blockIdx.x; tile < N / 32; tile += gridDim.x) {
    const size_t base = (size_t)tile * 32 * H;
    // stage pre tile -> LDS (padded rows of 136 shorts)
    {
      const uint4* srcp = (const uint4*)(pre_g + base);
#pragma unroll
      for (int it = 0; it < 2; ++it) {
        const int chunk = it * 256 + tid;  // 512 chunks of 8 bf16
        const int row = chunk >> 4;
        const int colc = (chunk & 15) * 8;
        *(uint4*)&preS[row * 136 + colc] = srcp[chunk];
      }
    }
    __syncthreads();

    // GEMM1: hid = relu(pre @ W1 + b1)
    {
      floatx4 acc[2][2];
#pragma unroll
      for (int i = 0; i < 2; ++i)
#pragma unroll
        for (int j = 0; j < 2; ++j) acc[i][j] = {0.f, 0.f, 0.f, 0.f};
#pragma unroll
      for (int kt = 0; kt < 4; ++kt) {
        const int kc = kt * 32 + quad * 8;
        const bf16x8 a0 =
            __builtin_bit_cast(bf16x8, *(const uint4*)&preS[l16 * 136 + kc]);
        const bf16x8 a1 = __builtin_bit_cast(
            bf16x8, *(const uint4*)&preS[(16 + l16) * 136 + kc]);
        acc[0][0] = __builtin_amdgcn_mfma_f32_16x16x32_bf16(a0, w1f[kt][0],
                                                            acc[0][0], 0, 0, 0);
        acc[0][1] = __builtin_amdgcn_mfma_f32_16x16x32_bf16(a0, w1f[kt][1],
                                                            acc[0][1], 0, 0, 0);
        acc[1][0] = __builtin_amdgcn_mfma_f32_16x16x32_bf16(a1, w1f[kt][0],
                                                            acc[1][0], 0, 0, 0);
        acc[1][1] = __builtin_amdgcn_mfma_f32_16x16x32_bf16(a1, w1f[kt][1],
                                                            acc[1][1], 0, 0, 0);
      }
#pragma unroll
      for (int mt = 0; mt < 2; ++mt)
#pragma unroll
        for (int nn = 0; nn < 2; ++nn) {
          const int col = wave * 32 + nn * 16 + l16;
#pragma unroll
          for (int r = 0; r < 4; ++r) {
            const int row = mt * 16 + quad * 4 + r;
            const float v = fmaxf(acc[mt][nn][r] + b1v[nn], 0.f);
            hidS[row * 136 + col] = f2b(v);
          }
        }
    }
    __syncthreads();

    // GEMM2: o = hid @ W2 + b2
    {
      floatx4 acc[2][2];
#pragma unroll
      for (int i = 0; i < 2; ++i)
#pragma unroll
        for (int j = 0; j < 2; ++j) acc[i][j] = {0.f, 0.f, 0.f, 0.f};
#pragma unroll
      for (int kt = 0; kt < 4; ++kt) {
        const int kc = kt * 32 + quad * 8;
        const bf16x8 a0 =
            __builtin_bit_cast(bf16x8, *(const uint4*)&hidS[l16 * 136 + kc]);
        const bf16x8 a1 = __builtin_bit_cast(
            bf16x8, *(const uint4*)&hidS[(16 + l16) * 136 + kc]);
        acc[0][0] = __builtin_amdgcn_mfma_f32_16x16x32_bf16(a0, w2f[kt][0],
                                                            acc[0][0], 0, 0, 0);
        acc[0][1] = __builtin_amdgcn_mfma_f32_16x16x32_bf16(a0, w2f[kt][1],
                                                            acc[0][1], 0, 0, 0);
        acc[1][0] = __builtin_amdgcn_mfma_f32_16x16x32_bf16(a1, w2f[kt][0],
                                                            acc[1][0], 0, 0, 0);
        acc[1][1] = __builtin_amdgcn_mfma_f32_16x16x32_bf16(a1, w2f[kt][1],
                                                            acc[1][1], 0, 0, 0);
      }
#pragma unroll
      for (int mt = 0; mt < 2; ++mt)
#pragma unroll
        for (int nn = 0; nn < 2; ++nn) {
          const int col = wave * 32 + nn * 16 + l16;
#pragma unroll
          for (int r = 0; r < 4; ++r) {
            const int row = mt * 16 + quad * 4 + r;
            float v = acc[mt][nn][r] + b2v[nn];
            if (MODE == 0) v = fmaxf(v, 0.f);  // relu before LN
            outS[row * 128 + col] = v;
          }
        }
    }
    __syncthreads();

    if (MODE == 0) {
      // LayerNorm over outS rows
      const int n = tid >> 3;
      const int j = tid & 7;
      float s = 0.f, sq = 0.f;
#pragma unroll
      for (int t = 0; t < 16; ++t) {
        const float v = outS[n * 128 + j + 8 * t];
        s += v;
        sq += v * v;
      }
      s += __shfl_xor(s, 1); sq += __shfl_xor(sq, 1);
      s += __shfl_xor(s, 2); sq += __shfl_xor(sq, 2);
      s += __shfl_xor(s, 4); sq += __shfl_xor(sq, 4);
      if (j == 0) {
        const float mu = s * (1.f / H);
        const float var = sq * (1.f / H) - mu * mu;
        muS[n] = mu;
        rsS[n] = rsqrtf(var + 1e-5f);
      }
      __syncthreads();
      unsigned* ho = (unsigned*)(h_out + base);
#pragma unroll
      for (int it = 0; it < 8; ++it) {
        const int idx = it * 512 + tid * 2;
        const int row = idx >> 7;
        const float mu = muS[row], rs = rsS[row];
        const float v0 = (outS[idx] - mu) * rs * lng0 + lnb0;
        const float v1 = (outS[idx + 1] - mu) * rs * lng1 + lnb1;
        ho[idx >> 1] = pack2(v0, v1);
      }
    } else {
      unsigned* ho = (unsigned*)(h_out + base);
#pragma unroll
      for (int it = 0; it < 8; ++it) {
        const int idx = it * 512 + tid * 2;
        const float v0 = outS[idx];
        const float v1 = outS[idx + 1];
        *(float2*)&emb[base + idx] = make_float2(v0, v1);
        ho[idx >> 1] = pack2(fmaxf(v0, 0.f), fmaxf(v1, 0.f));
      }
    }
    __syncthreads();  // all LDS reads done before next tile's writes
  }
}

// ---------------------------------------------------------------------------
// Mean-pool prep (bf16 input): batch sorted -> run-length accumulate.
// ---------------------------------------------------------------------------
constexpr int POOL_CHUNK = 512;
__global__ __launch_bounds__(128) void pool_kernel(
    const unsigned short* __restrict__ h, const int* __restrict__ batch,
    float* __restrict__ pooled, float* __restrict__ cnt) {
  const int f = threadIdx.x;
  const int s0 = blockIdx.x * POOL_CHUNK;
  const int s1 = min(s0 + POOL_CHUNK, N);
  float acc = 0.f;
  float c = 0.f;
  int cur = batch[s0];
  for (int n = s0; n < s1; ++n) {
    const int b = batch[n];
    if (b != cur) {
      atomicAdd(&pooled[cur * H + f], acc);
      if (f == 0) atomicAdd(&cnt[cur], c);
      acc = 0.f;
      c = 0.f;
      cur = b;
    }
    acc += b2f(h[(size_t)n * H + f]);
    c += 1.f;
  }
  atomicAdd(&pooled[cur * H + f], acc);
  if (f == 0) atomicAdd(&cnt[cur], c);
}

// ---------------------------------------------------------------------------
// Head: pooled/cnt -> z = pooled@pw1+pb1 -> logits -> log_softmax
// ---------------------------------------------------------------------------
__global__ __launch_bounds__(128) void head_kernel(
    const float* __restrict__ pooled, const float* __restrict__ cnt,
    const float* __restrict__ pw1, const float* __restrict__ pb1,
    const float* __restrict__ pw2, const float* __restrict__ pb2,
    float* __restrict__ out_logp) {
  __shared__ float p[H];
  __shared__ float z[H];
  __shared__ float l[C];
  const int g = blockIdx.x;
  const int f = threadIdx.x;
  const float c = fmaxf(cnt[g], 1.f);
  p[f] = pooled[g * H + f] / c;
  __syncthreads();
  float a = pb1[f];
  for (int k = 0; k < H; ++k) a += p[k] * pw1[k * H + f];
  z[f] = a;
  __syncthreads();
  if (f < C) {
    float a2 = pb2[f];
    for (int k = 0; k < H; ++k) a2 += z[k] * pw2[k * C + f];
    l[f] = a2;
  }
  __syncthreads();
  if (f == 0) {
    float m = l[0];
    for (int i = 1; i < C; ++i) m = fmaxf(m, l[i]);
    float s = 0.f;
    for (int i = 0; i < C; ++i) s += expf(l[i] - m);
    const float lse = m + logf(s);
    for (int i = 0; i < C; ++i) out_logp[g * C + i] = l[i] - lse;
  }
}

extern "C" void kernel_launch(void* const* d_in, const int* in_sizes, int n_in,
                              void* d_out, int out_size, void* d_ws,
                              size_t ws_size, hipStream_t stream) {
  const float* x = (const float*)d_in[0];
  const int* ei = (const int*)d_in[1];
  const int* src = ei;
  const int* dst = ei + E;
  const int* batch = (const int*)d_in[2];
  const float* w1_0 = (const float*)d_in[3];
  const float* b1_0 = (const float*)d_in[4];
  const float* w2_0 = (const float*)d_in[5];
  const float* b2_0 = (const float*)d_in[6];
  const float* w1_1 = (const float*)d_in[7];
  const float* b1_1 = (const float*)d_in[8];
  const float* w2_1 = (const float*)d_in[9];
  const float* b2_1 = (const float*)d_in[10];
  const float* w1_2 = (const float*)d_in[11];
  const float* b1_2 = (const float*)d_in[12];
  const float* w2_2 = (const float*)d_in[13];
  const float* b2_2 = (const float*)d_in[14];
  const float* ln_g0 = (const float*)d_in[15];
  const float* ln_b0 = (const float*)d_in[16];
  const float* ln_g1 = (const float*)d_in[17];
  const float* ln_b1 = (const float*)d_in[18];
  const float* pw1 = (const float*)d_in[19];
  const float* pb1 = (const float*)d_in[20];
  const float* pw2 = (const float*)d_in[21];
  const float* pb2 = (const float*)d_in[22];

  unsigned short* xb = (unsigned short*)d_ws;          // N*H bf16
  unsigned short* hb = xb + (size_t)N * H;             // N*H bf16
  unsigned short* pre = hb + (size_t)N * H;            // N*H bf16
  float* pooled = (float*)(pre + (size_t)N * H);       // G*H
  float* cnt = pooled + (size_t)G * H;                 // G
  int* deg = (int*)(cnt + G);                          // N
  int* rowptr = deg + N;                               // N+1
  int* cursor = rowptr + N + 1;                        // N
  int* csr_src = cursor + N;                           // E
  int* partials = csr_src + E;                         // NBLK
  int* blockbase = partials + NBLK;                    // NBLK
  float* emb = (float*)d_out;                          // N*H fp32
  float* logp = emb + (size_t)N * H;                   // G*C

  // ---- x -> bf16 ----
  tobf_kernel<<<N * H / (256 * 8), 256, 0, stream>>>(x, (uint4*)xb);

  // ---- CSR build ----
  hipMemsetAsync(deg, 0, (size_t)N * sizeof(int), stream);
  hist_kernel<<<E / 256, 256, 0, stream>>>(dst, deg);
  partial_kernel<<<NBLK, 256, 0, stream>>>(deg, partials);
  scanp_kernel<<<1, 512, 0, stream>>>(partials, blockbase);
  expand_kernel<<<NBLK, 256, 0, stream>>>(deg, blockbase, rowptr, cursor);
  fill_kernel<<<E / 256, 256, 0, stream>>>(src, dst, cursor, csr_src);

  // ---- conv 0 ----
  gather_kernel<<<N / 16, 256, 0, stream>>>((const uint4*)xb, rowptr, csr_src,
                                            (uint4*)pre);
  mlp_kernel<0><<<640, 256, 0, stream>>>(pre, w1_0, b1_0, w2_0, b2_0, ln_g0,
                                         ln_b0, hb, nullptr);
  // ---- conv 1 ----
  gather_kernel<<<N / 16, 256, 0, stream>>>((const uint4*)hb, rowptr, csr_src,
                                            (uint4*)pre);
  mlp_kernel<0><<<640, 256, 0, stream>>>(pre, w1_1, b1_1, w2_1, b2_1, ln_g1,
                                         ln_b1, hb, nullptr);
  // ---- conv 2 ----
  gather_kernel<<<N / 16, 256, 0, stream>>>((const uint4*)hb, rowptr, csr_src,
                                            (uint4*)pre);
  mlp_kernel<1><<<640, 256, 0, stream>>>(pre, w1_2, b1_2, w2_2, b2_2, nullptr,
                                         nullptr, hb, emb);
  // ---- pool + head ----
  hipMemsetAsync(pooled, 0, (size_t)(G * H + G) * sizeof(float), stream);
  pool_kernel<<<(N + POOL_CHUNK - 1) / POOL_CHUNK, 128, 0, stream>>>(
      hb, batch, pooled, cnt);
  head_kernel<<<G, 128, 0, stream>>>(pooled, cnt, pw1, pb1, pw2, pb2, logp);
}

// Round 4
// 629.763 us; speedup vs baseline: 14.5774x; 1.2126x over previous
//
#include <hip/hip_runtime.h>

typedef __bf16 bf16_t;
typedef __bf16 bf16x8 __attribute__((ext_vector_type(8)));
typedef float floatx4 __attribute__((ext_vector_type(4)));

constexpr int N = 100000;   // nodes
constexpr int E = 1600000;  // edges
constexpr int H = 128;      // feature dim
constexpr int G = 64;       // graphs
constexpr int C = 10;       // classes
constexpr int NBLK = (N + 255) / 256;  // 391

__device__ inline float bflo(unsigned u) {
  return __builtin_bit_cast(float, u << 16);
}
__device__ inline float bfhi(unsigned u) {
  return __builtin_bit_cast(float, u & 0xffff0000u);
}
__device__ inline unsigned short f2b(float f) {
  return __builtin_bit_cast(unsigned short, (bf16_t)f);
}
__device__ inline unsigned pack2(float a, float b) {
  return (unsigned)f2b(a) | ((unsigned)f2b(b) << 16);
}

// ---------------------------------------------------------------------------
// fp32 -> bf16 convert (x once per call). 8 floats/thread.
// ---------------------------------------------------------------------------
__global__ __launch_bounds__(256) void tobf_kernel(const float* __restrict__ x,
                                                   uint4* __restrict__ xb) {
  const int g = blockIdx.x * 256 + threadIdx.x;
  const float4 a = *(const float4*)(x + (size_t)g * 8);
  const float4 b = *(const float4*)(x + (size_t)g * 8 + 4);
  uint4 o;
  o.x = pack2(a.x, a.y);
  o.y = pack2(a.z, a.w);
  o.z = pack2(b.x, b.y);
  o.w = pack2(b.z, b.w);
  xb[g] = o;
}

// ---------------------------------------------------------------------------
// CSR build: histogram -> parallel 3-phase scan -> bucket fill.
// ---------------------------------------------------------------------------
__global__ __launch_bounds__(256) void hist_kernel(const int* __restrict__ dst,
                                                   int* __restrict__ deg) {
  const int e = blockIdx.x * 256 + threadIdx.x;
  if (e < E) atomicAdd(&deg[dst[e]], 1);
}

__global__ __launch_bounds__(256) void partial_kernel(
    const int* __restrict__ deg, int* __restrict__ partials) {
  __shared__ int sm[256];
  const int tid = threadIdx.x;
  const int i = blockIdx.x * 256 + tid;
  sm[tid] = (i < N) ? deg[i] : 0;
  __syncthreads();
  for (int off = 128; off > 0; off >>= 1) {
    if (tid < off) sm[tid] += sm[tid + off];
    __syncthreads();
  }
  if (tid == 0) partials[blockIdx.x] = sm[0];
}

__global__ __launch_bounds__(512) void scanp_kernel(
    const int* __restrict__ partials, int* __restrict__ blockbase) {
  __shared__ int p[512];
  const int t = threadIdx.x;
  p[t] = (t < NBLK) ? partials[t] : 0;
  __syncthreads();
  for (int off = 1; off < 512; off <<= 1) {
    int v = 0;
    if (t >= off) v = p[t - off];
    __syncthreads();
    p[t] += v;
    __syncthreads();
  }
  if (t < NBLK) blockbase[t] = (t == 0) ? 0 : p[t - 1];
}

__global__ __launch_bounds__(256) void expand_kernel(
    const int* __restrict__ deg, const int* __restrict__ blockbase,
    int* __restrict__ rowptr, int* __restrict__ cursor) {
  __shared__ int sm[256];
  const int tid = threadIdx.x;
  const int i = blockIdx.x * 256 + tid;
  const int d = (i < N) ? deg[i] : 0;
  sm[tid] = d;
  __syncthreads();
  for (int off = 1; off < 256; off <<= 1) {
    int v = 0;
    if (tid >= off) v = sm[tid - off];
    __syncthreads();
    sm[tid] += v;
    __syncthreads();
  }
  const int excl = sm[tid] - d + blockbase[blockIdx.x];
  if (i < N) {
    rowptr[i] = excl;
    cursor[i] = excl;
  }
  if (i == N - 1) rowptr[N] = excl + d;
}

__global__ __launch_bounds__(256) void fill_kernel(const int* __restrict__ src,
                                                   const int* __restrict__ dst,
                                                   int* __restrict__ cursor,
                                                   int* __restrict__ csr_src) {
  const int e = blockIdx.x * 256 + threadIdx.x;
  if (e < E) {
    const int slot = atomicAdd(&cursor[dst[e]], 1);
    csr_src[slot] = src[e];
  }
}

// ---------------------------------------------------------------------------
// Gather aggregation (bf16): pre[i] = h[i] + sum_{j in nbrs(i)} h[j]
// 16 lanes per node, uint4 (8 bf16) per lane. fp32 accumulate, bf16 out.
// ---------------------------------------------------------------------------
__global__ __launch_bounds__(256) void gather_kernel(
    const uint4* __restrict__ h, const int* __restrict__ rowptr,
    const int* __restrict__ csr_src, uint4* __restrict__ pre) {
  const int node = blockIdx.x * 16 + (threadIdx.x >> 4);
  const int l = threadIdx.x & 15;
  const int r0 = rowptr[node];
  const int r1 = rowptr[node + 1];
  uint4 v = h[node * 16 + l];
  float a0 = bflo(v.x), a1 = bfhi(v.x), a2 = bflo(v.y), a3 = bfhi(v.y);
  float a4 = bflo(v.z), a5 = bfhi(v.z), a6 = bflo(v.w), a7 = bfhi(v.w);
  int s = r0;
  for (; s + 1 < r1; s += 2) {
    const uint4 u = h[csr_src[s] * 16 + l];
    const uint4 w = h[csr_src[s + 1] * 16 + l];
    a0 += bflo(u.x); a1 += bfhi(u.x); a2 += bflo(u.y); a3 += bfhi(u.y);
    a4 += bflo(u.z); a5 += bfhi(u.z); a6 += bflo(u.w); a7 += bfhi(u.w);
    a0 += bflo(w.x); a1 += bfhi(w.x); a2 += bflo(w.y); a3 += bfhi(w.y);
    a4 += bflo(w.z); a5 += bfhi(w.z); a6 += bflo(w.w); a7 += bfhi(w.w);
  }
  if (s < r1) {
    const uint4 u = h[csr_src[s] * 16 + l];
    a0 += bflo(u.x); a1 += bfhi(u.x); a2 += bflo(u.y); a3 += bfhi(u.y);
    a4 += bflo(u.z); a5 += bfhi(u.z); a6 += bflo(u.w); a7 += bfhi(u.w);
  }
  uint4 o;
  o.x = pack2(a0, a1);
  o.y = pack2(a2, a3);
  o.z = pack2(a4, a5);
  o.w = pack2(a6, a7);
  pre[node * 16 + l] = o;
}

// ---------------------------------------------------------------------------
// MFMA bf16 GIN MLP. 32-node tiles; W1/W2 fragments in registers (loaded once
// per persistent block); pre/hid in LDS padded to 136 shorts (2-way bank
// aliasing = free). mfma_f32_16x16x32_bf16: A[m=lane&15][k=quad*8+j],
// B[k=quad*8+j][n=lane&15], C/D col=lane&15 row=quad*4+reg.
// MODE 0: h_out = bf16(LayerNorm(relu(o)))     (layers 0,1)
// MODE 1: emb = fp32 o; h_out = bf16(relu(o))  (layer 2)
// ---------------------------------------------------------------------------
template <int MODE>
__global__ __launch_bounds__(256, 1) void mlp_kernel(
    const unsigned short* __restrict__ pre_g,  // bf16 N x 128
    const float* __restrict__ w1, const float* __restrict__ b1,
    const float* __restrict__ w2, const float* __restrict__ b2,
    const float* __restrict__ lng, const float* __restrict__ lnb,
    unsigned short* __restrict__ h_out,        // bf16 N x 128
    float* __restrict__ emb) {
  __shared__ unsigned short preS[32 * 136];
  __shared__ unsigned short hidS[32 * 136];
  __shared__ float outS[32 * 128];
  __shared__ float muS[32];
  __shared__ float rsS[32];

  const int tid = threadIdx.x;
  const int wave = tid >> 6;
  const int lane = tid & 63;
  const int quad = lane >> 4;
  const int l16 = lane & 15;

  union F8 { bf16x8 v; bf16_t e[8]; };

  // Weight fragments in registers (once per block).
  bf16x8 w1f[4][2], w2f[4][2];
#pragma unroll
  for (int nn = 0; nn < 2; ++nn) {
    const int col = wave * 32 + nn * 16 + l16;
#pragma unroll
    for (int kt = 0; kt < 4; ++kt) {
      F8 t1, t2;
#pragma unroll
      for (int j = 0; j < 8; ++j) {
        const int k = kt * 32 + quad * 8 + j;
        t1.e[j] = (bf16_t)w1[k * H + col];
        t2.e[j] = (bf16_t)w2[k * H + col];
      }
      w1f[kt][nn] = t1.v;
      w2f[kt][nn] = t2.v;
    }
  }
  const float b1v[2] = {b1[wave * 32 + l16], b1[wave * 32 + 16 + l16]};
  const float b2v[2] = {b2[wave * 32 + l16], b2[wave * 32 + 16 + l16]};
  float lng0 = 0.f, lng1 = 0.f, lnb0 = 0.f, lnb1 = 0.f;
  const int c2 = (tid * 2) & 127;
  if (MODE == 0) {
    lng0 = lng[c2]; lng1 = lng[c2 + 1];
    lnb0 = lnb[c2]; lnb1 = lnb[c2 + 1];
  }

  for (int tile = blockIdx.x; tile < N / 32; tile += gridDim.x) {
    const size_t base = (size_t)tile * 32 * H;
    // stage pre tile -> LDS (padded rows of 136 shorts)
    {
      const uint4* srcp = (const uint4*)(pre_g + base);
#pragma unroll
      for (int it = 0; it < 2; ++it) {
        const int chunk = it * 256 + tid;  // 512 chunks of 8 bf16
        const int row = chunk >> 4;
        const int colc = (chunk & 15) * 8;
        *(uint4*)&preS[row * 136 + colc] = srcp[chunk];
      }
    }
    __syncthreads();

    // GEMM1: hid = relu(pre @ W1 + b1)
    {
      floatx4 acc[2][2];
#pragma unroll
      for (int i = 0; i < 2; ++i)
#pragma unroll
        for (int j = 0; j < 2; ++j) acc[i][j] = {0.f, 0.f, 0.f, 0.f};
#pragma unroll
      for (int kt = 0; kt < 4; ++kt) {
        const int kc = kt * 32 + quad * 8;
        const bf16x8 a0 =
            __builtin_bit_cast(bf16x8, *(const uint4*)&preS[l16 * 136 + kc]);
        const bf16x8 a1 = __builtin_bit_cast(
            bf16x8, *(const uint4*)&preS[(16 + l16) * 136 + kc]);
        acc[0][0] = __builtin_amdgcn_mfma_f32_16x16x32_bf16(a0, w1f[kt][0],
                                                            acc[0][0], 0, 0, 0);
        acc[0][1] = __builtin_amdgcn_mfma_f32_16x16x32_bf16(a0, w1f[kt][1],
                                                            acc[0][1], 0, 0, 0);
        acc[1][0] = __builtin_amdgcn_mfma_f32_16x16x32_bf16(a1, w1f[kt][0],
                                                            acc[1][0], 0, 0, 0);
        acc[1][1] = __builtin_amdgcn_mfma_f32_16x16x32_bf16(a1, w1f[kt][1],
                                                            acc[1][1], 0, 0, 0);
      }
#pragma unroll
      for (int mt = 0; mt < 2; ++mt)
#pragma unroll
        for (int nn = 0; nn < 2; ++nn) {
          const int col = wave * 32 + nn * 16 + l16;
#pragma unroll
          for (int r = 0; r < 4; ++r) {
            const int row = mt * 16 + quad * 4 + r;
            const float v = fmaxf(acc[mt][nn][r] + b1v[nn], 0.f);
            hidS[row * 136 + col] = f2b(v);
          }
        }
    }
    __syncthreads();

    // GEMM2: o = hid @ W2 + b2
    {
      floatx4 acc[2][2];
#pragma unroll
      for (int i = 0; i < 2; ++i)
#pragma unroll
        for (int j = 0; j < 2; ++j) acc[i][j] = {0.f, 0.f, 0.f, 0.f};
#pragma unroll
      for (int kt = 0; kt < 4; ++kt) {
        const int kc = kt * 32 + quad * 8;
        const bf16x8 a0 =
            __builtin_bit_cast(bf16x8, *(const uint4*)&hidS[l16 * 136 + kc]);
        const bf16x8 a1 = __builtin_bit_cast(
            bf16x8, *(const uint4*)&hidS[(16 + l16) * 136 + kc]);
        acc[0][0] = __builtin_amdgcn_mfma_f32_16x16x32_bf16(a0, w2f[kt][0],
                                                            acc[0][0], 0, 0, 0);
        acc[0][1] = __builtin_amdgcn_mfma_f32_16x16x32_bf16(a0, w2f[kt][1],
                                                            acc[0][1], 0, 0, 0);
        acc[1][0] = __builtin_amdgcn_mfma_f32_16x16x32_bf16(a1, w2f[kt][0],
                                                            acc[1][0], 0, 0, 0);
        acc[1][1] = __builtin_amdgcn_mfma_f32_16x16x32_bf16(a1, w2f[kt][1],
                                                            acc[1][1], 0, 0, 0);
      }
#pragma unroll
      for (int mt = 0; mt < 2; ++mt)
#pragma unroll
        for (int nn = 0; nn < 2; ++nn) {
          const int col = wave * 32 + nn * 16 + l16;
#pragma unroll
          for (int r = 0; r < 4; ++r) {
            const int row = mt * 16 + quad * 4 + r;
            float v = acc[mt][nn][r] + b2v[nn];
            if (MODE == 0) v = fmaxf(v, 0.f);  // relu before LN
            outS[row * 128 + col] = v;
          }
        }
    }
    __syncthreads();

    if (MODE == 0) {
      // LayerNorm over outS rows
      const int n = tid >> 3;
      const int j = tid & 7;
      float s = 0.f, sq = 0.f;
#pragma unroll
      for (int t = 0; t < 16; ++t) {
        const float v = outS[n * 128 + j + 8 * t];
        s += v;
        sq += v * v;
      }
      s += __shfl_xor(s, 1); sq += __shfl_xor(sq, 1);
      s += __shfl_xor(s, 2); sq += __shfl_xor(sq, 2);
      s += __shfl_xor(s, 4); sq += __shfl_xor(sq, 4);
      if (j == 0) {
        const float mu = s * (1.f / H);
        const float var = sq * (1.f / H) - mu * mu;
        muS[n] = mu;
        rsS[n] = rsqrtf(var + 1e-5f);
      }
      __syncthreads();
      unsigned* ho = (unsigned*)(h_out + base);
#pragma unroll
      for (int it = 0; it < 8; ++it) {
        const int idx = it * 512 + tid * 2;
        const int row = idx >> 7;
        const float mu = muS[row], rs = rsS[row];
        const float v0 = (outS[idx] - mu) * rs * lng0 + lnb0;
        const float v1 = (outS[idx + 1] - mu) * rs * lng1 + lnb1;
        ho[idx >> 1] = pack2(v0, v1);
      }
    } else {
      unsigned* ho = (unsigned*)(h_out + base);
#pragma unroll
      for (int it = 0; it < 8; ++it) {
        const int idx = it * 512 + tid * 2;
        const float v0 = outS[idx];
        const float v1 = outS[idx + 1];
        *(float2*)&emb[base + idx] = make_float2(v0, v1);
        ho[idx >> 1] = pack2(fmaxf(v0, 0.f), fmaxf(v1, 0.f));
      }
    }
    __syncthreads();  // all LDS reads done before next tile's writes
  }
}

// ---------------------------------------------------------------------------
// Mean pool: cooperative segmented reduction over sorted `batch`.
// Block = 256 sorted nodes; run boundaries via LDS atomicMin; each thread
// accumulates 8 feats (uint4 loads); shfl_xor(16/32) + cross-wave LDS
// reduce; one 128-atomic flush per run.
// ---------------------------------------------------------------------------
__global__ __launch_bounds__(256) void pool_kernel(
    const uint4* __restrict__ hv, const int* __restrict__ batch,
    float* __restrict__ pooled, float* __restrict__ cnt) {
  __shared__ int bs[256];
  __shared__ float smr[512];
  __shared__ int endS;
  const int tid = threadIdx.x;
  const int c0 = blockIdx.x * 256;
  const int len = min(256, N - c0);
  if (tid < len) bs[tid] = batch[c0 + tid];
  __syncthreads();

  const int nl = tid >> 4;   // node lane 0..15
  const int fg = tid & 15;   // feature group (8 feats)
  const int wave = tid >> 6;
  const int lane = tid & 63;

  int start = 0;
  while (start < len) {
    const int g = bs[start];
    if (tid == 0) endS = len;
    __syncthreads();
    for (int i = start + tid; i < len; i += 256)
      if (bs[i] != g) atomicMin(&endS, i);
    __syncthreads();
    const int end = endS;

    float a0 = 0.f, a1 = 0.f, a2 = 0.f, a3 = 0.f;
    float a4 = 0.f, a5 = 0.f, a6 = 0.f, a7 = 0.f;
    for (int i = start + nl; i < end; i += 16) {
      const uint4 u = hv[(size_t)(c0 + i) * 16 + fg];
      a0 += bflo(u.x); a1 += bfhi(u.x); a2 += bflo(u.y); a3 += bfhi(u.y);
      a4 += bflo(u.z); a5 += bfhi(u.z); a6 += bflo(u.w); a7 += bfhi(u.w);
    }
    // collapse the 4 node-lanes within this wave (tid bits 4,5)
    a0 += __shfl_xor(a0, 16); a1 += __shfl_xor(a1, 16);
    a2 += __shfl_xor(a2, 16); a3 += __shfl_xor(a3, 16);
    a4 += __shfl_xor(a4, 16); a5 += __shfl_xor(a5, 16);
    a6 += __shfl_xor(a6, 16); a7 += __shfl_xor(a7, 16);
    a0 += __shfl_xor(a0, 32); a1 += __shfl_xor(a1, 32);
    a2 += __shfl_xor(a2, 32); a3 += __shfl_xor(a3, 32);
    a4 += __shfl_xor(a4, 32); a5 += __shfl_xor(a5, 32);
    a6 += __shfl_xor(a6, 32); a7 += __shfl_xor(a7, 32);
    if (lane < 16) {
      float* d = &smr[wave * 128 + lane * 8];
      d[0] = a0; d[1] = a1; d[2] = a2; d[3] = a3;
      d[4] = a4; d[5] = a5; d[6] = a6; d[7] = a7;
    }
    __syncthreads();
    if (tid < 128) {
      const float s =
          smr[tid] + smr[128 + tid] + smr[256 + tid] + smr[384 + tid];
      atomicAdd(&pooled[g * H + tid], s);
    }
    if (tid == 0) atomicAdd(&cnt[g], (float)(end - start));
    __syncthreads();
    start = end;
  }
}

// ---------------------------------------------------------------------------
// Head: pooled/cnt -> z = pooled@pw1+pb1 -> logits -> log_softmax
// ---------------------------------------------------------------------------
__global__ __launch_bounds__(128) void head_kernel(
    const float* __restrict__ pooled, const float* __restrict__ cnt,
    const float* __restrict__ pw1, const float* __restrict__ pb1,
    const float* __restrict__ pw2, const float* __restrict__ pb2,
    float* __restrict__ out_logp) {
  __shared__ float p[H];
  __shared__ float z[H];
  __shared__ float l[C];
  const int g = blockIdx.x;
  const int f = threadIdx.x;
  const float c = fmaxf(cnt[g], 1.f);
  p[f] = pooled[g * H + f] / c;
  __syncthreads();
  float a = pb1[f];
  for (int k = 0; k < H; ++k) a += p[k] * pw1[k * H + f];
  z[f] = a;
  __syncthreads();
  if (f < C) {
    float a2 = pb2[f];
    for (int k = 0; k < H; ++k) a2 += z[k] * pw2[k * C + f];
    l[f] = a2;
  }
  __syncthreads();
  if (f == 0) {
    float m = l[0];
    for (int i = 1; i < C; ++i) m = fmaxf(m, l[i]);
    float s = 0.f;
    for (int i = 0; i < C; ++i) s += expf(l[i] - m);
    const float lse = m + logf(s);
    for (int i = 0; i < C; ++i) out_logp[g * C + i] = l[i] - lse;
  }
}

extern "C" void kernel_launch(void* const* d_in, const int* in_sizes, int n_in,
                              void* d_out, int out_size, void* d_ws,
                              size_t ws_size, hipStream_t stream) {
  const float* x = (const float*)d_in[0];
  const int* ei = (const int*)d_in[1];
  const int* src = ei;
  const int* dst = ei + E;
  const int* batch = (const int*)d_in[2];
  const float* w1_0 = (const float*)d_in[3];
  const float* b1_0 = (const float*)d_in[4];
  const float* w2_0 = (const float*)d_in[5];
  const float* b2_0 = (const float*)d_in[6];
  const float* w1_1 = (const float*)d_in[7];
  const float* b1_1 = (const float*)d_in[8];
  const float* w2_1 = (const float*)d_in[9];
  const float* b2_1 = (const float*)d_in[10];
  const float* w1_2 = (const float*)d_in[11];
  const float* b1_2 = (const float*)d_in[12];
  const float* w2_2 = (const float*)d_in[13];
  const float* b2_2 = (const float*)d_in[14];
  const float* ln_g0 = (const float*)d_in[15];
  const float* ln_b0 = (const float*)d_in[16];
  const float* ln_g1 = (const float*)d_in[17];
  const float* ln_b1 = (const float*)d_in[18];
  const float* pw1 = (const float*)d_in[19];
  const float* pb1 = (const float*)d_in[20];
  const float* pw2 = (const float*)d_in[21];
  const float* pb2 = (const float*)d_in[22];

  unsigned short* xb = (unsigned short*)d_ws;          // N*H bf16
  unsigned short* hb = xb + (size_t)N * H;             // N*H bf16
  unsigned short* pre = hb + (size_t)N * H;            // N*H bf16
  float* pooled = (float*)(pre + (size_t)N * H);       // G*H
  float* cnt = pooled + (size_t)G * H;                 // G
  int* deg = (int*)(cnt + G);                          // N
  int* rowptr = deg + N;                               // N+1
  int* cursor = rowptr + N + 1;                        // N
  int* csr_src = cursor + N;                           // E
  int* partials = csr_src + E;                         // NBLK
  int* blockbase = partials + NBLK;                    // NBLK
  float* emb = (float*)d_out;                          // N*H fp32
  float* logp = emb + (size_t)N * H;                   // G*C

  // ---- x -> bf16 ----
  tobf_kernel<<<N * H / (256 * 8), 256, 0, stream>>>(x, (uint4*)xb);

  // ---- CSR build ----
  hipMemsetAsync(deg, 0, (size_t)N * sizeof(int), stream);
  hist_kernel<<<E / 256, 256, 0, stream>>>(dst, deg);
  partial_kernel<<<NBLK, 256, 0, stream>>>(deg, partials);
  scanp_kernel<<<1, 512, 0, stream>>>(partials, blockbase);
  expand_kernel<<<NBLK, 256, 0, stream>>>(deg, blockbase, rowptr, cursor);
  fill_kernel<<<E / 256, 256, 0, stream>>>(src, dst, cursor, csr_src);

  // ---- conv 0 ----
  gather_kernel<<<N / 16, 256, 0, stream>>>((const uint4*)xb, rowptr, csr_src,
                                            (uint4*)pre);
  mlp_kernel<0><<<640, 256, 0, stream>>>(pre, w1_0, b1_0, w2_0, b2_0, ln_g0,
                                         ln_b0, hb, nullptr);
  // ---- conv 1 ----
  gather_kernel<<<N / 16, 256, 0, stream>>>((const uint4*)hb, rowptr, csr_src,
                                            (uint4*)pre);
  mlp_kernel<0><<<640, 256, 0, stream>>>(pre, w1_1, b1_1, w2_1, b2_1, ln_g1,
                                         ln_b1, hb, nullptr);
  // ---- conv 2 ----
  gather_kernel<<<N / 16, 256, 0, stream>>>((const uint4*)hb, rowptr, csr_src,
                                            (uint4*)pre);
  mlp_kernel<1><<<640, 256, 0, stream>>>(pre, w1_2, b1_2, w2_2, b2_2, nullptr,
                                         nullptr, hb, emb);
  // ---- pool + head ----
  hipMemsetAsync(pooled, 0, (size_t)(G * H + G) * sizeof(float), stream);
  pool_kernel<<<NBLK, 256, 0, stream>>>((const uint4*)hb, batch, pooled, cnt);
  head_kernel<<<G, 128, 0, stream>>>(pooled, cnt, pw1, pb1, pw2, pb2, logp);
}

// Round 5
// 583.368 us; speedup vs baseline: 15.7367x; 1.0795x over previous
//
#include <hip/hip_runtime.h>

typedef __bf16 bf16_t;
typedef __bf16 bf16x8 __attribute__((ext_vector_type(8)));
typedef float floatx4 __attribute__((ext_vector_type(4)));

constexpr int N = 100000;   // nodes
constexpr int E = 1600000;  // edges
constexpr int H = 128;      // feature dim
constexpr int G = 64;       // graphs
constexpr int C = 10;       // classes
constexpr int NBLK = (N + 255) / 256;  // 391

// CSR-build partitioning: 8 node ranges (XCD-local L2 footprints) x 256
// edge chunks. blockIdx % 8 == range so round-robin dispatch pins a range
// to one XCD.
constexpr int NPART = 8;
constexpr int PART_SZ = (N + NPART - 1) / NPART;  // 12500
constexpr int NCHUNK = 256;
constexpr int CHUNK_E = E / NCHUNK;  // 6250

__device__ inline float bflo(unsigned u) {
  return __builtin_bit_cast(float, u << 16);
}
__device__ inline float bfhi(unsigned u) {
  return __builtin_bit_cast(float, u & 0xffff0000u);
}
__device__ inline unsigned short f2b(float f) {
  return __builtin_bit_cast(unsigned short, (bf16_t)f);
}
__device__ inline unsigned pack2(float a, float b) {
  return (unsigned)f2b(a) | ((unsigned)f2b(b) << 16);
}

// ---------------------------------------------------------------------------
// fp32 -> bf16 convert (x once per call). 8 floats/thread.
// ---------------------------------------------------------------------------
__global__ __launch_bounds__(256) void tobf_kernel(const float* __restrict__ x,
                                                   uint4* __restrict__ xb) {
  const int g = blockIdx.x * 256 + threadIdx.x;
  const float4 a = *(const float4*)(x + (size_t)g * 8);
  const float4 b = *(const float4*)(x + (size_t)g * 8 + 4);
  uint4 o;
  o.x = pack2(a.x, a.y);
  o.y = pack2(a.z, a.w);
  o.z = pack2(b.x, b.y);
  o.w = pack2(b.z, b.w);
  xb[g] = o;
}

// ---------------------------------------------------------------------------
// CSR build: partitioned histogram -> parallel 3-phase scan -> partitioned
// bucket fill. Each block scans one edge chunk but touches only dst nodes in
// its range -> deg/cursor/csr writes stay in one XCD's L2.
// ---------------------------------------------------------------------------
__global__ __launch_bounds__(256) void hist_kernel(const int* __restrict__ dst,
                                                   int* __restrict__ deg) {
  const int part = blockIdx.x & (NPART - 1);
  const int chunk = blockIdx.x / NPART;
  const int lo = part * PART_SZ;
  const int hi = lo + PART_SZ;
  const int c0 = chunk * CHUNK_E;
  const int c1 = c0 + CHUNK_E;
  for (int e = c0 + threadIdx.x; e < c1; e += 256) {
    const int d = dst[e];
    if (d >= lo && d < hi) atomicAdd(&deg[d], 1);
  }
}

__global__ __launch_bounds__(256) void partial_kernel(
    const int* __restrict__ deg, int* __restrict__ partials) {
  __shared__ int sm[256];
  const int tid = threadIdx.x;
  const int i = blockIdx.x * 256 + tid;
  sm[tid] = (i < N) ? deg[i] : 0;
  __syncthreads();
  for (int off = 128; off > 0; off >>= 1) {
    if (tid < off) sm[tid] += sm[tid + off];
    __syncthreads();
  }
  if (tid == 0) partials[blockIdx.x] = sm[0];
}

__global__ __launch_bounds__(512) void scanp_kernel(
    const int* __restrict__ partials, int* __restrict__ blockbase) {
  __shared__ int p[512];
  const int t = threadIdx.x;
  p[t] = (t < NBLK) ? partials[t] : 0;
  __syncthreads();
  for (int off = 1; off < 512; off <<= 1) {
    int v = 0;
    if (t >= off) v = p[t - off];
    __syncthreads();
    p[t] += v;
    __syncthreads();
  }
  if (t < NBLK) blockbase[t] = (t == 0) ? 0 : p[t - 1];
}

__global__ __launch_bounds__(256) void expand_kernel(
    const int* __restrict__ deg, const int* __restrict__ blockbase,
    int* __restrict__ rowptr, int* __restrict__ cursor) {
  __shared__ int sm[256];
  const int tid = threadIdx.x;
  const int i = blockIdx.x * 256 + tid;
  const int d = (i < N) ? deg[i] : 0;
  sm[tid] = d;
  __syncthreads();
  for (int off = 1; off < 256; off <<= 1) {
    int v = 0;
    if (tid >= off) v = sm[tid - off];
    __syncthreads();
    sm[tid] += v;
    __syncthreads();
  }
  const int excl = sm[tid] - d + blockbase[blockIdx.x];
  if (i < N) {
    rowptr[i] = excl;
    cursor[i] = excl;
  }
  if (i == N - 1) rowptr[N] = excl + d;
}

__global__ __launch_bounds__(256) void fill_kernel(const int* __restrict__ src,
                                                   const int* __restrict__ dst,
                                                   int* __restrict__ cursor,
                                                   int* __restrict__ csr_src) {
  const int part = blockIdx.x & (NPART - 1);
  const int chunk = blockIdx.x / NPART;
  const int lo = part * PART_SZ;
  const int hi = lo + PART_SZ;
  const int c0 = chunk * CHUNK_E;
  const int c1 = c0 + CHUNK_E;
  for (int e = c0 + threadIdx.x; e < c1; e += 256) {
    const int d = dst[e];
    if (d >= lo && d < hi) {
      const int slot = atomicAdd(&cursor[d], 1);
      csr_src[slot] = src[e];
    }
  }
}

// ---------------------------------------------------------------------------
// Gather aggregation (bf16): pre[i] = h[i] + sum_{j in nbrs(i)} h[j]
// 16 lanes per node, uint4 (8 bf16) per lane. fp32 accumulate, bf16 out.
// ---------------------------------------------------------------------------
__global__ __launch_bounds__(256) void gather_kernel(
    const uint4* __restrict__ h, const int* __restrict__ rowptr,
    const int* __restrict__ csr_src, uint4* __restrict__ pre) {
  const int node = blockIdx.x * 16 + (threadIdx.x >> 4);
  const int l = threadIdx.x & 15;
  const int r0 = rowptr[node];
  const int r1 = rowptr[node + 1];
  uint4 v = h[node * 16 + l];
  float a0 = bflo(v.x), a1 = bfhi(v.x), a2 = bflo(v.y), a3 = bfhi(v.y);
  float a4 = bflo(v.z), a5 = bfhi(v.z), a6 = bflo(v.w), a7 = bfhi(v.w);
  int s = r0;
  for (; s + 1 < r1; s += 2) {
    const uint4 u = h[csr_src[s] * 16 + l];
    const uint4 w = h[csr_src[s + 1] * 16 + l];
    a0 += bflo(u.x); a1 += bfhi(u.x); a2 += bflo(u.y); a3 += bfhi(u.y);
    a4 += bflo(u.z); a5 += bfhi(u.z); a6 += bflo(u.w); a7 += bfhi(u.w);
    a0 += bflo(w.x); a1 += bfhi(w.x); a2 += bflo(w.y); a3 += bfhi(w.y);
    a4 += bflo(w.z); a5 += bfhi(w.z); a6 += bflo(w.w); a7 += bfhi(w.w);
  }
  if (s < r1) {
    const uint4 u = h[csr_src[s] * 16 + l];
    a0 += bflo(u.x); a1 += bfhi(u.x); a2 += bflo(u.y); a3 += bfhi(u.y);
    a4 += bflo(u.z); a5 += bfhi(u.z); a6 += bflo(u.w); a7 += bfhi(u.w);
  }
  uint4 o;
  o.x = pack2(a0, a1);
  o.y = pack2(a2, a3);
  o.z = pack2(a4, a5);
  o.w = pack2(a6, a7);
  pre[node * 16 + l] = o;
}

// ---------------------------------------------------------------------------
// MFMA bf16 GIN MLP. 32-node tiles; W1/W2 fragments in registers; pre/hid in
// LDS padded to 136 shorts. MODE 0: LN(relu(o)); MODE 1: emb + relu(o).
// ---------------------------------------------------------------------------
template <int MODE>
__global__ __launch_bounds__(256, 1) void mlp_kernel(
    const unsigned short* __restrict__ pre_g,  // bf16 N x 128
    const float* __restrict__ w1, const float* __restrict__ b1,
    const float* __restrict__ w2, const float* __restrict__ b2,
    const float* __restrict__ lng, const float* __restrict__ lnb,
    unsigned short* __restrict__ h_out,        // bf16 N x 128
    float* __restrict__ emb) {
  __shared__ unsigned short preS[32 * 136];
  __shared__ unsigned short hidS[32 * 136];
  __shared__ float outS[32 * 128];
  __shared__ float muS[32];
  __shared__ float rsS[32];

  const int tid = threadIdx.x;
  const int wave = tid >> 6;
  const int lane = tid & 63;
  const int quad = lane >> 4;
  const int l16 = lane & 15;

  union F8 { bf16x8 v; bf16_t e[8]; };

  bf16x8 w1f[4][2], w2f[4][2];
#pragma unroll
  for (int nn = 0; nn < 2; ++nn) {
    const int col = wave * 32 + nn * 16 + l16;
#pragma unroll
    for (int kt = 0; kt < 4; ++kt) {
      F8 t1, t2;
#pragma unroll
      for (int j = 0; j < 8; ++j) {
        const int k = kt * 32 + quad * 8 + j;
        t1.e[j] = (bf16_t)w1[k * H + col];
        t2.e[j] = (bf16_t)w2[k * H + col];
      }
      w1f[kt][nn] = t1.v;
      w2f[kt][nn] = t2.v;
    }
  }
  const float b1v[2] = {b1[wave * 32 + l16], b1[wave * 32 + 16 + l16]};
  const float b2v[2] = {b2[wave * 32 + l16], b2[wave * 32 + 16 + l16]};
  float lng0 = 0.f, lng1 = 0.f, lnb0 = 0.f, lnb1 = 0.f;
  const int c2 = (tid * 2) & 127;
  if (MODE == 0) {
    lng0 = lng[c2]; lng1 = lng[c2 + 1];
    lnb0 = lnb[c2]; lnb1 = lnb[c2 + 1];
  }

  for (int tile = blockIdx.x; tile < N / 32; tile += gridDim.x) {
    const size_t base = (size_t)tile * 32 * H;
    {
      const uint4* srcp = (const uint4*)(pre_g + base);
#pragma unroll
      for (int it = 0; it < 2; ++it) {
        const int chunk = it * 256 + tid;
        const int row = chunk >> 4;
        const int colc = (chunk & 15) * 8;
        *(uint4*)&preS[row * 136 + colc] = srcp[chunk];
      }
    }
    __syncthreads();

    // GEMM1: hid = relu(pre @ W1 + b1)
    {
      floatx4 acc[2][2];
#pragma unroll
      for (int i = 0; i < 2; ++i)
#pragma unroll
        for (int j = 0; j < 2; ++j) acc[i][j] = {0.f, 0.f, 0.f, 0.f};
#pragma unroll
      for (int kt = 0; kt < 4; ++kt) {
        const int kc = kt * 32 + quad * 8;
        const bf16x8 a0 =
            __builtin_bit_cast(bf16x8, *(const uint4*)&preS[l16 * 136 + kc]);
        const bf16x8 a1 = __builtin_bit_cast(
            bf16x8, *(const uint4*)&preS[(16 + l16) * 136 + kc]);
        acc[0][0] = __builtin_amdgcn_mfma_f32_16x16x32_bf16(a0, w1f[kt][0],
                                                            acc[0][0], 0, 0, 0);
        acc[0][1] = __builtin_amdgcn_mfma_f32_16x16x32_bf16(a0, w1f[kt][1],
                                                            acc[0][1], 0, 0, 0);
        acc[1][0] = __builtin_amdgcn_mfma_f32_16x16x32_bf16(a1, w1f[kt][0],
                                                            acc[1][0], 0, 0, 0);
        acc[1][1] = __builtin_amdgcn_mfma_f32_16x16x32_bf16(a1, w1f[kt][1],
                                                            acc[1][1], 0, 0, 0);
      }
#pragma unroll
      for (int mt = 0; mt < 2; ++mt)
#pragma unroll
        for (int nn = 0; nn < 2; ++nn) {
          const int col = wave * 32 + nn * 16 + l16;
#pragma unroll
          for (int r = 0; r < 4; ++r) {
            const int row = mt * 16 + quad * 4 + r;
            const float v = fmaxf(acc[mt][nn][r] + b1v[nn], 0.f);
            hidS[row * 136 + col] = f2b(v);
          }
        }
    }
    __syncthreads();

    // GEMM2: o = hid @ W2 + b2
    {
      floatx4 acc[2][2];
#pragma unroll
      for (int i = 0; i < 2; ++i)
#pragma unroll
        for (int j = 0; j < 2; ++j) acc[i][j] = {0.f, 0.f, 0.f, 0.f};
#pragma unroll
      for (int kt = 0; kt < 4; ++kt) {
        const int kc = kt * 32 + quad * 8;
        const bf16x8 a0 =
            __builtin_bit_cast(bf16x8, *(const uint4*)&hidS[l16 * 136 + kc]);
        const bf16x8 a1 = __builtin_bit_cast(
            bf16x8, *(const uint4*)&hidS[(16 + l16) * 136 + kc]);
        acc[0][0] = __builtin_amdgcn_mfma_f32_16x16x32_bf16(a0, w2f[kt][0],
                                                            acc[0][0], 0, 0, 0);
        acc[0][1] = __builtin_amdgcn_mfma_f32_16x16x32_bf16(a0, w2f[kt][1],
                                                            acc[0][1], 0, 0, 0);
        acc[1][0] = __builtin_amdgcn_mfma_f32_16x16x32_bf16(a1, w2f[kt][0],
                                                            acc[1][0], 0, 0, 0);
        acc[1][1] = __builtin_amdgcn_mfma_f32_16x16x32_bf16(a1, w2f[kt][1],
                                                            acc[1][1], 0, 0, 0);
      }
#pragma unroll
      for (int mt = 0; mt < 2; ++mt)
#pragma unroll
        for (int nn = 0; nn < 2; ++nn) {
          const int col = wave * 32 + nn * 16 + l16;
#pragma unroll
          for (int r = 0; r < 4; ++r) {
            const int row = mt * 16 + quad * 4 + r;
            float v = acc[mt][nn][r] + b2v[nn];
            if (MODE == 0) v = fmaxf(v, 0.f);
            outS[row * 128 + col] = v;
          }
        }
    }
    __syncthreads();

    if (MODE == 0) {
      const int n = tid >> 3;
      const int j = tid & 7;
      float s = 0.f, sq = 0.f;
#pragma unroll
      for (int t = 0; t < 16; ++t) {
        const float v = outS[n * 128 + j + 8 * t];
        s += v;
        sq += v * v;
      }
      s += __shfl_xor(s, 1); sq += __shfl_xor(sq, 1);
      s += __shfl_xor(s, 2); sq += __shfl_xor(sq, 2);
      s += __shfl_xor(s, 4); sq += __shfl_xor(sq, 4);
      if (j == 0) {
        const float mu = s * (1.f / H);
        const float var = sq * (1.f / H) - mu * mu;
        muS[n] = mu;
        rsS[n] = rsqrtf(var + 1e-5f);
      }
      __syncthreads();
      unsigned* ho = (unsigned*)(h_out + base);
#pragma unroll
      for (int it = 0; it < 8; ++it) {
        const int idx = it * 512 + tid * 2;
        const int row = idx >> 7;
        const float mu = muS[row], rs = rsS[row];
        const float v0 = (outS[idx] - mu) * rs * lng0 + lnb0;
        const float v1 = (outS[idx + 1] - mu) * rs * lng1 + lnb1;
        ho[idx >> 1] = pack2(v0, v1);
      }
    } else {
      unsigned* ho = (unsigned*)(h_out + base);
#pragma unroll
      for (int it = 0; it < 8; ++it) {
        const int idx = it * 512 + tid * 2;
        const float v0 = outS[idx];
        const float v1 = outS[idx + 1];
        *(float2*)&emb[base + idx] = make_float2(v0, v1);
        ho[idx >> 1] = pack2(fmaxf(v0, 0.f), fmaxf(v1, 0.f));
      }
    }
    __syncthreads();
  }
}

// ---------------------------------------------------------------------------
// Mean pool: cooperative segmented reduction over sorted `batch`.
// ---------------------------------------------------------------------------
__global__ __launch_bounds__(256) void pool_kernel(
    const uint4* __restrict__ hv, const int* __restrict__ batch,
    float* __restrict__ pooled, float* __restrict__ cnt) {
  __shared__ int bs[256];
  __shared__ float smr[512];
  __shared__ int endS;
  const int tid = threadIdx.x;
  const int c0 = blockIdx.x * 256;
  const int len = min(256, N - c0);
  if (tid < len) bs[tid] = batch[c0 + tid];
  __syncthreads();

  const int nl = tid >> 4;
  const int fg = tid & 15;
  const int wave = tid >> 6;
  const int lane = tid & 63;

  int start = 0;
  while (start < len) {
    const int g = bs[start];
    if (tid == 0) endS = len;
    __syncthreads();
    for (int i = start + tid; i < len; i += 256)
      if (bs[i] != g) atomicMin(&endS, i);
    __syncthreads();
    const int end = endS;

    float a0 = 0.f, a1 = 0.f, a2 = 0.f, a3 = 0.f;
    float a4 = 0.f, a5 = 0.f, a6 = 0.f, a7 = 0.f;
    for (int i = start + nl; i < end; i += 16) {
      const uint4 u = hv[(size_t)(c0 + i) * 16 + fg];
      a0 += bflo(u.x); a1 += bfhi(u.x); a2 += bflo(u.y); a3 += bfhi(u.y);
      a4 += bflo(u.z); a5 += bfhi(u.z); a6 += bflo(u.w); a7 += bfhi(u.w);
    }
    a0 += __shfl_xor(a0, 16); a1 += __shfl_xor(a1, 16);
    a2 += __shfl_xor(a2, 16); a3 += __shfl_xor(a3, 16);
    a4 += __shfl_xor(a4, 16); a5 += __shfl_xor(a5, 16);
    a6 += __shfl_xor(a6, 16); a7 += __shfl_xor(a7, 16);
    a0 += __shfl_xor(a0, 32); a1 += __shfl_xor(a1, 32);
    a2 += __shfl_xor(a2, 32); a3 += __shfl_xor(a3, 32);
    a4 += __shfl_xor(a4, 32); a5 += __shfl_xor(a5, 32);
    a6 += __shfl_xor(a6, 32); a7 += __shfl_xor(a7, 32);
    if (lane < 16) {
      float* d = &smr[wave * 128 + lane * 8];
      d[0] = a0; d[1] = a1; d[2] = a2; d[3] = a3;
      d[4] = a4; d[5] = a5; d[6] = a6; d[7] = a7;
    }
    __syncthreads();
    if (tid < 128) {
      const float s =
          smr[tid] + smr[128 + tid] + smr[256 + tid] + smr[384 + tid];
      atomicAdd(&pooled[g * H + tid], s);
    }
    if (tid == 0) atomicAdd(&cnt[g], (float)(end - start));
    __syncthreads();
    start = end;
  }
}

// ---------------------------------------------------------------------------
// Head: pooled/cnt -> z = pooled@pw1+pb1 -> logits -> log_softmax
// ---------------------------------------------------------------------------
__global__ __launch_bounds__(128) void head_kernel(
    const float* __restrict__ pooled, const float* __restrict__ cnt,
    const float* __restrict__ pw1, const float* __restrict__ pb1,
    const float* __restrict__ pw2, const float* __restrict__ pb2,
    float* __restrict__ out_logp) {
  __shared__ float p[H];
  __shared__ float z[H];
  __shared__ float l[C];
  const int g = blockIdx.x;
  const int f = threadIdx.x;
  const float c = fmaxf(cnt[g], 1.f);
  p[f] = pooled[g * H + f] / c;
  __syncthreads();
  float a = pb1[f];
  for (int k = 0; k < H; ++k) a += p[k] * pw1[k * H + f];
  z[f] = a;
  __syncthreads();
  if (f < C) {
    float a2 = pb2[f];
    for (int k = 0; k < H; ++k) a2 += z[k] * pw2[k * C + f];
    l[f] = a2;
  }
  __syncthreads();
  if (f == 0) {
    float m = l[0];
    for (int i = 1; i < C; ++i) m = fmaxf(m, l[i]);
    float s = 0.f;
    for (int i = 0; i < C; ++i) s += expf(l[i] - m);
    const float lse = m + logf(s);
    for (int i = 0; i < C; ++i) out_logp[g * C + i] = l[i] - lse;
  }
}

extern "C" void kernel_launch(void* const* d_in, const int* in_sizes, int n_in,
                              void* d_out, int out_size, void* d_ws,
                              size_t ws_size, hipStream_t stream) {
  const float* x = (const float*)d_in[0];
  const int* ei = (const int*)d_in[1];
  const int* src = ei;
  const int* dst = ei + E;
  const int* batch = (const int*)d_in[2];
  const float* w1_0 = (const float*)d_in[3];
  const float* b1_0 = (const float*)d_in[4];
  const float* w2_0 = (const float*)d_in[5];
  const float* b2_0 = (const float*)d_in[6];
  const float* w1_1 = (const float*)d_in[7];
  const float* b1_1 = (const float*)d_in[8];
  const float* w2_1 = (const float*)d_in[9];
  const float* b2_1 = (const float*)d_in[10];
  const float* w1_2 = (const float*)d_in[11];
  const float* b1_2 = (const float*)d_in[12];
  const float* w2_2 = (const float*)d_in[13];
  const float* b2_2 = (const float*)d_in[14];
  const float* ln_g0 = (const float*)d_in[15];
  const float* ln_b0 = (const float*)d_in[16];
  const float* ln_g1 = (const float*)d_in[17];
  const float* ln_b1 = (const float*)d_in[18];
  const float* pw1 = (const float*)d_in[19];
  const float* pb1 = (const float*)d_in[20];
  const float* pw2 = (const float*)d_in[21];
  const float* pb2 = (const float*)d_in[22];

  unsigned short* xb = (unsigned short*)d_ws;          // N*H bf16
  unsigned short* hb = xb + (size_t)N * H;             // N*H bf16
  unsigned short* pre = hb + (size_t)N * H;            // N*H bf16
  float* pooled = (float*)(pre + (size_t)N * H);       // G*H
  float* cnt = pooled + (size_t)G * H;                 // G
  int* deg = (int*)(cnt + G);                          // N
  int* rowptr = deg + N;                               // N+1
  int* cursor = rowptr + N + 1;                        // N
  int* csr_src = cursor + N;                           // E
  int* partials = csr_src + E;                         // NBLK
  int* blockbase = partials + NBLK;                    // NBLK
  float* emb = (float*)d_out;                          // N*H fp32
  float* logp = emb + (size_t)N * H;                   // G*C

  // ---- x -> bf16 ----
  tobf_kernel<<<N * H / (256 * 8), 256, 0, stream>>>(x, (uint4*)xb);

  // ---- CSR build (XCD-partitioned) ----
  hipMemsetAsync(deg, 0, (size_t)N * sizeof(int), stream);
  hist_kernel<<<NCHUNK * NPART, 256, 0, stream>>>(dst, deg);
  partial_kernel<<<NBLK, 256, 0, stream>>>(deg, partials);
  scanp_kernel<<<1, 512, 0, stream>>>(partials, blockbase);
  expand_kernel<<<NBLK, 256, 0, stream>>>(deg, blockbase, rowptr, cursor);
  fill_kernel<<<NCHUNK * NPART, 256, 0, stream>>>(src, dst, cursor, csr_src);

  // ---- conv 0 ----
  gather_kernel<<<N / 16, 256, 0, stream>>>((const uint4*)xb, rowptr, csr_src,
                                            (uint4*)pre);
  mlp_kernel<0><<<640, 256, 0, stream>>>(pre, w1_0, b1_0, w2_0, b2_0, ln_g0,
                                         ln_b0, hb, nullptr);
  // ---- conv 1 ----
  gather_kernel<<<N / 16, 256, 0, stream>>>((const uint4*)hb, rowptr, csr_src,
                                            (uint4*)pre);
  mlp_kernel<0><<<640, 256, 0, stream>>>(pre, w1_1, b1_1, w2_1, b2_1, ln_g1,
                                         ln_b1, hb, nullptr);
  // ---- conv 2 ----
  gather_kernel<<<N / 16, 256, 0, stream>>>((const uint4*)hb, rowptr, csr_src,
                                            (uint4*)pre);
  mlp_kernel<1><<<640, 256, 0, stream>>>(pre, w1_2, b1_2, w2_2, b2_2, nullptr,
                                         nullptr, hb, emb);
  // ---- pool + head ----
  hipMemsetAsync(pooled, 0, (size_t)(G * H + G) * sizeof(float), stream);
  pool_kernel<<<NBLK, 256, 0, stream>>>((const uint4*)hb, batch, pooled, cnt);
  head_kernel<<<G, 128, 0, stream>>>(pooled, cnt, pw1, pb1, pw2, pb2, logp);
}